// Round 1
// baseline (3129.866 us; speedup 1.0000x reference)
//
#include <hip/hip_runtime.h>
#include <stdint.h>

// Problem constants
#define TOKS 2048           // B*S
#define SEQ 1024
#define DM 256
#define NEGV -1e9f

// ---------------- dtype helpers ----------------
__device__ __forceinline__ float loadf(const void* p, size_t i, int isbf16) {
  if (isbf16) {
    unsigned short u = ((const unsigned short*)p)[i];
    return __uint_as_float(((unsigned)u) << 16);
  }
  return ((const float*)p)[i];
}

__device__ __forceinline__ unsigned short f32_to_bf16(float f) {
  unsigned u = __float_as_uint(f);
  unsigned r = u + 0x7FFFu + ((u >> 16) & 1u);
  return (unsigned short)(r >> 16);
}

// ---------------- detection ----------------
// flags[0]: 1 if float tensors are bf16, 0 if f32
// flags[1]: 1 if bool tensors are 1-byte, 0 if int32
__global__ void k_detect(const void* fs, const void* bs, int* flags) {
  int lane = threadIdx.x; // 64 threads
  int bad = 0;
  for (int i = lane; i < 256; i += 64) {
    unsigned short u = ((const unsigned short*)fs)[i];
    float v = __uint_as_float(((unsigned)u) << 16);
    if (!(fabsf(v) <= 100.f)) bad = 1;   // catches huge / inf / nan
  }
  int big = 0;
  for (int i = lane; i < 512; i += 64) {
    if (((const unsigned*)bs)[i] > 1u) big = 1;
  }
#pragma unroll
  for (int off = 32; off; off >>= 1) {
    bad |= __shfl_xor(bad, off);
    big |= __shfl_xor(big, off);
  }
  if (lane == 0) { flags[0] = bad ? 0 : 1; flags[1] = big ? 1 : 0; }
}

// ---------------- canonicalization ----------------
struct ConvEntry { const void* src; float* dst; int n; };
struct ConvArgs { ConvEntry e[28]; };

__global__ void k_convert_many(ConvArgs ca, const int* __restrict__ flags) {
  int isbf = flags[0];
  ConvEntry E = ca.e[blockIdx.y];
  for (int i = blockIdx.x * 256 + threadIdx.x; i < E.n; i += gridDim.x * 256)
    E.dst[i] = loadf(E.src, (size_t)i, isbf);
}

__global__ void k_convert_bools(const void* pad, const void* msk,
                                unsigned char* pb, unsigned char* mb,
                                const int* __restrict__ flags) {
  int isb = flags[1];
  int i = blockIdx.x * 256 + threadIdx.x;
  if (i < TOKS) {
    if (isb) {
      pb[i] = ((const unsigned char*)pad)[i] ? 1 : 0;
      mb[i] = ((const unsigned char*)msk)[i] ? 1 : 0;
    } else {
      pb[i] = (((const int*)pad)[i] != 0) ? 1 : 0;
      mb[i] = (((const int*)msk)[i] != 0) ? 1 : 0;
    }
  }
}

// Wqkv_cat[i][k][l*768 + w*256 + n] = W_w[i,l][k][n]   (w: 0=q,1=k,2=v)
__global__ void k_convert_qkv(const void* wq, const void* wk, const void* wv,
                              float* __restrict__ dst, const int* __restrict__ flags) {
  int isbf = flags[0];
  int t = blockIdx.x * 256 + threadIdx.x;
  if (t >= 2 * 256 * 3072) return;
  int i = t / 786432;
  int rem = t % 786432;
  int k = rem / 3072;
  int c = rem % 3072;
  int l = c / 768;
  int w = (c % 768) / 256;
  int n = c % 256;
  const void* src = (w == 0) ? wq : ((w == 1) ? wk : wv);
  size_t si = ((size_t)((i * 4 + l) * 256 + k)) * 256 + n;
  dst[t] = loadf(src, si, isbf);
}

// ---------------- pairwise mask bits ----------------
// mb[b][q][k]: bit0 feat, bit1 nbr, bit2 col, bit3 full
__global__ __launch_bounds__(256) void k_masks(
    const int* __restrict__ node, const int* __restrict__ f2p,
    const int* __restrict__ colid, const int* __restrict__ tabid,
    const unsigned char* __restrict__ pad_b, unsigned char* __restrict__ mb) {
  int b = blockIdx.y;
  int q = blockIdx.x;
  int base = b * SEQ;
  int nq = node[base + q];
  int cq = colid[base + q], tq = tabid[base + q];
  int pq = pad_b[base + q] ? 0 : 1;
  __shared__ int f2pq[8];
  if (threadIdx.x < 8) f2pq[threadIdx.x] = f2p[(size_t)(base + q) * 8 + threadIdx.x];
  __syncthreads();
  for (int k = threadIdx.x; k < SEQ; k += 256) {
    int nk = node[base + k];
    int pk = pad_b[base + k] ? 0 : 1;
    int padok = pq & pk;
    int kv_in = 0, q_in = 0;
#pragma unroll
    for (int t = 0; t < 8; t++) kv_in |= (nk == f2pq[t]);
    const int* fk = &f2p[(size_t)(base + k) * 8];
#pragma unroll
    for (int t = 0; t < 8; t++) q_in |= (nq == fk[t]);
    int feat = ((nq == nk) | kv_in);
    int col = (cq == colid[base + k]) & (tq == tabid[base + k]);
    unsigned char bits = 0;
    if (padok) bits = (unsigned char)((feat ? 1 : 0) | (q_in ? 2 : 0) | (col ? 4 : 0) | 8);
    mb[((size_t)base + q) * SEQ + k] = bits;
  }
}

// ---------------- block reductions / LN ----------------
__device__ __forceinline__ float block_sum256(float v, float* red) {
#pragma unroll
  for (int off = 32; off; off >>= 1) v += __shfl_xor(v, off);
  int w = threadIdx.x >> 6;
  __syncthreads();                      // protect red from previous use
  if ((threadIdx.x & 63) == 0) red[w] = v;
  __syncthreads();
  return red[0] + red[1] + red[2] + red[3];
}

__device__ __forceinline__ float ln256(float y, float* red) {
  float mean = block_sum256(y, red) * (1.0f / 256.0f);
  float dv = y - mean;
  float var = block_sum256(dv * dv, red) * (1.0f / 256.0f);
  return dv * rsqrtf(var + 1e-5f);
}

// ---------------- cell value encoder ----------------
__global__ __launch_bounds__(256) void k_encoder(
    const float* __restrict__ colv, const float* __restrict__ numv,
    const float* __restrict__ textv,
    const float* __restrict__ Wc, const float* __restrict__ bc,
    const float* __restrict__ Wn, const float* __restrict__ bn,
    const float* __restrict__ Wt, const float* __restrict__ bt,
    const float* __restrict__ gc, const float* __restrict__ bec,
    const float* __restrict__ gn, const float* __restrict__ ben,
    const float* __restrict__ gt, const float* __restrict__ bet,
    const float* __restrict__ men, const float* __restrict__ met,
    const unsigned char* __restrict__ pad_b, const unsigned char* __restrict__ msk_b,
    const int* __restrict__ sem, float* __restrict__ x) {
  __shared__ float row[384];
  __shared__ float red[4];
  int token = blockIdx.x, d = threadIdx.x;
  int ispad = pad_b[token];
  float notpad = ispad ? 0.f : 1.f;
  int st = sem[token];
  int mk = msk_b[token];

  for (int i = d; i < 384; i += 256) row[i] = colv[(size_t)token * 384 + i];
  __syncthreads();
  float y = bc[d];
  for (int j = 0; j < 384; j++) y += row[j] * Wc[j * 256 + d];
  float xv = (ln256(y, red) * gc[d] + bec[d]) * notpad;

  // numeric path (cheap: always compute LN, conditionally add)
  {
    float yn = numv[token] * Wn[d] + bn[d];
    float lnv = ln256(yn, red) * gn[d] + ben[d];
    if (st == 0 && !ispad && !mk) xv += lnv;
    if (st == 0 && !ispad && mk)  xv += men[d];
  }
  // text path (expensive: block-uniform condition, skip when unused)
  if (st == 1 && !ispad && !mk) {
    __syncthreads();
    for (int i = d; i < 384; i += 256) row[i] = textv[(size_t)token * 384 + i];
    __syncthreads();
    float yt = bt[d];
    for (int j = 0; j < 384; j++) yt += row[j] * Wt[j * 256 + d];
    xv += ln256(yt, red) * gt[d] + bet[d];
  }
  if (st == 1 && !ispad && mk) xv += met[d];
  x[(size_t)token * 256 + d] = xv;
}

// ---------------- generic LN kernel ----------------
__global__ __launch_bounds__(256) void k_ln(const float* __restrict__ xin,
                                            const float* __restrict__ g,
                                            const float* __restrict__ b,
                                            float* __restrict__ out) {
  __shared__ float red[4];
  int token = blockIdx.x, d = threadIdx.x;
  float v = xin[(size_t)token * 256 + d];
  out[(size_t)token * 256 + d] = ln256(v, red) * g[d] + b[d];
}

__global__ __launch_bounds__(256) void k_ln_out(const float* __restrict__ xin,
                                                const float* __restrict__ g,
                                                const float* __restrict__ b,
                                                void* __restrict__ out,
                                                const int* __restrict__ flags) {
  __shared__ float red[4];
  int token = blockIdx.x, d = threadIdx.x;
  float v = xin[(size_t)token * 256 + d];
  float o = ln256(v, red) * g[d] + b[d];
  size_t idx = (size_t)token * 256 + d;
  if (flags[0]) ((unsigned short*)out)[idx] = f32_to_bf16(o);
  else ((float*)out)[idx] = o;
}

// ---------------- GEMM: C[M,N] (+)= act(A[M,K] @ B[K,N] + bias) ----------------
__device__ __forceinline__ float gelu_tanh(float v) {
  const float c = 0.7978845608028654f; // sqrt(2/pi)
  float t = tanhf(c * (v + 0.044715f * v * v * v));
  return 0.5f * v * (1.f + t);
}

template <int ACT, int ACC>
__global__ __launch_bounds__(256) void k_gemm(
    const float* __restrict__ A, const float* __restrict__ Bm,
    const float* __restrict__ bias, float* __restrict__ C,
    int M, int N, int K) {
  __shared__ float As[16][65];   // [k][m]
  __shared__ float Bs[16][65];   // [k][n]
  int tid = threadIdx.x;
  int bm = blockIdx.y * 64, bn = blockIdx.x * 64;
  int tx = tid & 15, ty = tid >> 4;
  float acc[4][4] = {};
  for (int k0 = 0; k0 < K; k0 += 16) {
    {
      int m = tid >> 2, kk = (tid & 3) * 4;
      float4 av = *(const float4*)&A[(size_t)(bm + m) * K + k0 + kk];
      As[kk + 0][m] = av.x; As[kk + 1][m] = av.y;
      As[kk + 2][m] = av.z; As[kk + 3][m] = av.w;
      int kb = tid >> 4, nn = (tid & 15) * 4;
      float4 bv = *(const float4*)&Bm[(size_t)(k0 + kb) * N + bn + nn];
      Bs[kb][nn + 0] = bv.x; Bs[kb][nn + 1] = bv.y;
      Bs[kb][nn + 2] = bv.z; Bs[kb][nn + 3] = bv.w;
    }
    __syncthreads();
#pragma unroll
    for (int kk = 0; kk < 16; kk++) {
      float a0 = As[kk][ty * 4 + 0], a1 = As[kk][ty * 4 + 1];
      float a2 = As[kk][ty * 4 + 2], a3 = As[kk][ty * 4 + 3];
      float b0 = Bs[kk][tx * 4 + 0], b1 = Bs[kk][tx * 4 + 1];
      float b2 = Bs[kk][tx * 4 + 2], b3 = Bs[kk][tx * 4 + 3];
      acc[0][0] += a0 * b0; acc[0][1] += a0 * b1; acc[0][2] += a0 * b2; acc[0][3] += a0 * b3;
      acc[1][0] += a1 * b0; acc[1][1] += a1 * b1; acc[1][2] += a1 * b2; acc[1][3] += a1 * b3;
      acc[2][0] += a2 * b0; acc[2][1] += a2 * b1; acc[2][2] += a2 * b2; acc[2][3] += a2 * b3;
      acc[3][0] += a3 * b0; acc[3][1] += a3 * b1; acc[3][2] += a3 * b2; acc[3][3] += a3 * b3;
    }
    __syncthreads();
  }
#pragma unroll
  for (int i = 0; i < 4; i++) {
#pragma unroll
    for (int j = 0; j < 4; j++) {
      int n = bn + tx * 4 + j;
      float v = acc[i][j];
      if (bias) v += bias[n];
      if (ACT) v = gelu_tanh(v);
      size_t idx = (size_t)(bm + ty * 4 + i) * N + n;
      if (ACC) C[idx] += v; else C[idx] = v;
    }
  }
}

// ---------------- masked flash attention ----------------
// QKV: [2048][3072], col = l*768 + {0:q,256:k,512:v} + h*32 + dh
// Ocat: [2048][1024], col = l*256 + h*32 + dh
// grid: (S/16, H, B*4), block: 64 (one wave), 16 q-rows per wave
__global__ __launch_bounds__(64) void k_attn(
    const float* __restrict__ QKV, const unsigned char* __restrict__ mb,
    float* __restrict__ Ocat) {
  int lane = threadIdx.x;
  int qt = blockIdx.x * 16;
  int hh = blockIdx.y;
  int b = blockIdx.z >> 2, l = blockIdx.z & 3;
  __shared__ float qs[16][32];
  __shared__ float ks[64][33];
  __shared__ float vs[64][33];
  __shared__ float ps[16][64];
  const int qcol = l * 768 + hh * 32;
  const int kcol = qcol + 256;
  const int vcol = qcol + 512;
  const size_t tokbase = (size_t)b * SEQ;

  for (int e = lane; e < 512; e += 64) {
    int r = e >> 5, dd = e & 31;
    qs[r][dd] = QKV[(tokbase + qt + r) * 3072 + qcol + dd] * 0.17677669529663687f;
  }
  float m[16], ls[16], acc[16], sc[16];
#pragma unroll
  for (int r = 0; r < 16; r++) { m[r] = -1e30f; ls[r] = 0.f; acc[r] = 0.f; sc[r] = 1.f; }
  unsigned rowany = 0;
  int d = lane & 31, half = lane >> 5;

  for (int kc = 0; kc < SEQ; kc += 64) {
    __syncthreads();
    {
      const float* kp = &QKV[(tokbase + kc + lane) * 3072 + kcol];
      const float* vp = &QKV[(tokbase + kc + lane) * 3072 + vcol];
#pragma unroll
      for (int i = 0; i < 32; i += 4) {
        float4 kv = *(const float4*)(kp + i);
        ks[lane][i] = kv.x; ks[lane][i + 1] = kv.y; ks[lane][i + 2] = kv.z; ks[lane][i + 3] = kv.w;
        float4 vv = *(const float4*)(vp + i);
        vs[lane][i] = vv.x; vs[lane][i + 1] = vv.y; vs[lane][i + 2] = vv.z; vs[lane][i + 3] = vv.w;
      }
    }
    __syncthreads();
    const unsigned char* mrow = &mb[(tokbase + qt) * SEQ + kc + lane];
#pragma unroll
    for (int r = 0; r < 16; r++) {
      float s = 0.f;
#pragma unroll
      for (int i = 0; i < 32; i++) s += qs[r][i] * ks[lane][i];
      int ok = (mrow[(size_t)r * SEQ] >> l) & 1;
      s = ok ? s : NEGV;                       // exact -1e9 like the reference
      rowany |= ((unsigned)ok) << r;
      float cm = s;
#pragma unroll
      for (int off = 32; off; off >>= 1) cm = fmaxf(cm, __shfl_xor(cm, off));
      float mn = fmaxf(m[r], cm);
      float scale = __expf(m[r] - mn);
      float p = __expf(s - mn);
      float psum = p;
#pragma unroll
      for (int off = 32; off; off >>= 1) psum += __shfl_xor(psum, off);
      ls[r] = ls[r] * scale + psum;
      m[r] = mn;
      sc[r] = scale;
      ps[r][lane] = p;
    }
    __syncthreads();
#pragma unroll
    for (int r = 0; r < 16; r++) {
      float a = acc[r] * sc[r];
#pragma unroll
      for (int j = 0; j < 32; j++) a += ps[r][half * 32 + j] * vs[half * 32 + j][d];
      acc[r] = a;
    }
  }
#pragma unroll
  for (int off = 32; off; off >>= 1) rowany |= __shfl_xor(rowany, off);
#pragma unroll
  for (int r = 0; r < 16; r++) {
    float tot = acc[r] + __shfl_xor(acc[r], 32);
    float o = ((rowany >> r) & 1) ? (tot / ls[r]) : 0.f;
    if (lane < 32)
      Ocat[(tokbase + qt + r) * 1024 + l * 256 + hh * 32 + d] = o;
  }
}

// ---------------- host ----------------
extern "C" void kernel_launch(void* const* d_in, const int* in_sizes, int n_in,
                              void* d_out, int out_size, void* d_ws, size_t ws_size,
                              hipStream_t stream) {
  (void)n_in; (void)out_size; (void)ws_size;
  char* wsb = (char*)d_ws;
  int* flags = (int*)wsb;
  unsigned char* pad_b = (unsigned char*)(wsb + 256);
  unsigned char* msk_b = (unsigned char*)(wsb + 256 + 2048);
  unsigned char* mbits = (unsigned char*)(wsb + 8192);            // 2 MB
  float* fbase = (float*)(wsb + 8192 + 2 * 1024 * 1024);
  size_t fo = 0;
  auto alloc = [&](size_t n) { float* p = fbase + fo; fo += (n + 63) & ~(size_t)63; return p; };

  float* Wc = alloc(98304);  float* bc = alloc(256);
  float* Wn = alloc(256);    float* bn = alloc(256);
  float* Wt = alloc(98304);  float* bt = alloc(256);
  float* gc = alloc(256);    float* bec = alloc(256);
  float* gn = alloc(256);    float* ben = alloc(256);
  float* gt = alloc(256);    float* bet = alloc(256);
  float* men = alloc(256);   float* met = alloc(256);
  float* Wqkv = alloc(2 * 786432);
  float* Woc = alloc(524288);
  float* l1g = alloc(512);   float* l1b = alloc(512);
  float* l2g = alloc(512);   float* l2b = alloc(512);
  float* W1c = alloc(524288); float* b1c = alloc(2048);
  float* W2c = alloc(524288); float* b2c = alloc(512);
  float* goc = alloc(256);   float* beo = alloc(256);
  float* colv = alloc(786432); float* numv = alloc(2048); float* textv = alloc(786432);
  float* x = alloc(524288);
  float* h = alloc(524288);
  float* Ocat = alloc(2097152);
  float* QKV = alloc(6291456);
  float* fbuf = QKV;  // FFN hidden aliases QKV (QKV dead by then)

  k_detect<<<1, 64, 0, stream>>>(d_in[7], d_in[6], flags);
  k_convert_bools<<<8, 256, 0, stream>>>(d_in[4], d_in[6], pad_b, msk_b, flags);

  ConvArgs ca;
  const int idxs[28] = {10, 11, 12, 13, 14, 15, 16, 17, 18, 19, 20, 21, 22, 23,
                        27, 28, 29, 30, 31, 32, 33, 34, 35, 36, 37, 7, 8, 9};
  float* dsts[28] = {Wc, bc, Wn, bn, Wt, bt, gc, bec, gn, ben, gt, bet, men, met,
                     Woc, l1g, l1b, l2g, l2b, W1c, b1c, W2c, b2c, goc, beo,
                     colv, numv, textv};
  for (int t = 0; t < 28; t++) {
    ca.e[t].src = d_in[idxs[t]];
    ca.e[t].dst = dsts[t];
    ca.e[t].n = in_sizes[idxs[t]];
  }
  k_convert_many<<<dim3(64, 28), 256, 0, stream>>>(ca, flags);
  k_convert_qkv<<<(2 * 256 * 3072 + 255) / 256, 256, 0, stream>>>(
      d_in[24], d_in[25], d_in[26], Wqkv, flags);
  k_masks<<<dim3(1024, 2), 256, 0, stream>>>(
      (const int*)d_in[0], (const int*)d_in[1], (const int*)d_in[2],
      (const int*)d_in[3], pad_b, mbits);
  k_encoder<<<2048, 256, 0, stream>>>(colv, numv, textv, Wc, bc, Wn, bn, Wt, bt,
                                      gc, bec, gn, ben, gt, bet, men, met,
                                      pad_b, msk_b, (const int*)d_in[5], x);
  for (int i = 0; i < 2; i++) {
    k_ln<<<2048, 256, 0, stream>>>(x, l1g + i * 256, l1b + i * 256, h);
    k_gemm<0, 0><<<dim3(48, 32), 256, 0, stream>>>(h, Wqkv + (size_t)i * 786432,
                                                   nullptr, QKV, 2048, 3072, 256);
    k_attn<<<dim3(64, 8, 8), 64, 0, stream>>>(QKV, mbits, Ocat);
    k_gemm<0, 1><<<dim3(4, 32), 256, 0, stream>>>(Ocat, Woc + (size_t)i * 262144,
                                                  nullptr, x, 2048, 256, 1024);
    k_ln<<<2048, 256, 0, stream>>>(x, l2g + i * 256, l2b + i * 256, h);
    k_gemm<1, 0><<<dim3(16, 32), 256, 0, stream>>>(h, W1c + (size_t)i * 262144,
                                                   b1c + (size_t)i * 1024, fbuf,
                                                   2048, 1024, 256);
    k_gemm<0, 1><<<dim3(4, 32), 256, 0, stream>>>(fbuf, W2c + (size_t)i * 262144,
                                                  b2c + (size_t)i * 256, x,
                                                  2048, 256, 1024);
  }
  k_ln_out<<<2048, 256, 0, stream>>>(x, goc, beo, d_out, flags);
}

// Round 2
// 737.440 us; speedup vs baseline: 4.2442x; 4.2442x over previous
//
#include <hip/hip_runtime.h>
#include <stdint.h>

// Problem constants
#define TOKS 2048           // B*S
#define SEQ 1024
#define DM 256
#define NEGV -1e9f

typedef __attribute__((ext_vector_type(8))) short short8;
typedef __attribute__((ext_vector_type(4))) float f32x4;

// ---------------- dtype helpers ----------------
__device__ __forceinline__ float loadf(const void* p, size_t i, int isbf16) {
  if (isbf16) {
    unsigned short u = ((const unsigned short*)p)[i];
    return __uint_as_float(((unsigned)u) << 16);
  }
  return ((const float*)p)[i];
}

__device__ __forceinline__ unsigned short f32_to_bf16(float f) {
  unsigned u = __float_as_uint(f);
  unsigned r = u + 0x7FFFu + ((u >> 16) & 1u);
  return (unsigned short)(r >> 16);
}

__device__ __forceinline__ short8 cvt8(float4 a, float4 b) {
  short8 r;
  r[0] = (short)f32_to_bf16(a.x); r[1] = (short)f32_to_bf16(a.y);
  r[2] = (short)f32_to_bf16(a.z); r[3] = (short)f32_to_bf16(a.w);
  r[4] = (short)f32_to_bf16(b.x); r[5] = (short)f32_to_bf16(b.y);
  r[6] = (short)f32_to_bf16(b.z); r[7] = (short)f32_to_bf16(b.w);
  return r;
}

// ---------------- detection ----------------
// flags[0]: 1 if float tensors are bf16, 0 if f32
// flags[1]: 1 if bool tensors are 1-byte, 0 if int32
__global__ void k_detect(const void* fs, const void* bs, int* flags) {
  int lane = threadIdx.x; // 64 threads
  int bad = 0;
  for (int i = lane; i < 256; i += 64) {
    unsigned short u = ((const unsigned short*)fs)[i];
    float v = __uint_as_float(((unsigned)u) << 16);
    if (!(fabsf(v) <= 100.f)) bad = 1;   // catches huge / inf / nan
  }
  int big = 0;
  for (int i = lane; i < 512; i += 64) {
    if (((const unsigned*)bs)[i] > 1u) big = 1;
  }
#pragma unroll
  for (int off = 32; off; off >>= 1) {
    bad |= __shfl_xor(bad, off);
    big |= __shfl_xor(big, off);
  }
  if (lane == 0) { flags[0] = bad ? 0 : 1; flags[1] = big ? 1 : 0; }
}

// ---------------- canonicalization ----------------
struct ConvEntry { const void* src; float* dst; int n; };
struct ConvArgs { ConvEntry e[28]; };

__global__ void k_convert_many(ConvArgs ca, const int* __restrict__ flags) {
  int isbf = flags[0];
  ConvEntry E = ca.e[blockIdx.y];
  for (int i = blockIdx.x * 256 + threadIdx.x; i < E.n; i += gridDim.x * 256)
    E.dst[i] = loadf(E.src, (size_t)i, isbf);
}

__global__ void k_convert_bools(const void* pad, const void* msk,
                                unsigned char* pb, unsigned char* mb,
                                const int* __restrict__ flags) {
  int isb = flags[1];
  int i = blockIdx.x * 256 + threadIdx.x;
  if (i < TOKS) {
    if (isb) {
      pb[i] = ((const unsigned char*)pad)[i] ? 1 : 0;
      mb[i] = ((const unsigned char*)msk)[i] ? 1 : 0;
    } else {
      pb[i] = (((const int*)pad)[i] != 0) ? 1 : 0;
      mb[i] = (((const int*)msk)[i] != 0) ? 1 : 0;
    }
  }
}

// Wqkv_cat[i][k][l*768 + w*256 + n] = W_w[i,l][k][n]   (w: 0=q,1=k,2=v)
__global__ void k_convert_qkv(const void* wq, const void* wk, const void* wv,
                              float* __restrict__ dst, const int* __restrict__ flags) {
  int isbf = flags[0];
  int t = blockIdx.x * 256 + threadIdx.x;
  if (t >= 2 * 256 * 3072) return;
  int i = t / 786432;
  int rem = t % 786432;
  int k = rem / 3072;
  int c = rem % 3072;
  int l = c / 768;
  int w = (c % 768) / 256;
  int n = c % 256;
  const void* src = (w == 0) ? wq : ((w == 1) ? wk : wv);
  size_t si = ((size_t)((i * 4 + l) * 256 + k)) * 256 + n;
  dst[t] = loadf(src, si, isbf);
}

// ---------------- pairwise mask bits ----------------
// mb[b][q][k]: bit0 feat, bit1 nbr, bit2 col, bit3 full
__global__ __launch_bounds__(256) void k_masks(
    const int* __restrict__ node, const int* __restrict__ f2p,
    const int* __restrict__ colid, const int* __restrict__ tabid,
    const unsigned char* __restrict__ pad_b, unsigned char* __restrict__ mb) {
  int b = blockIdx.y;
  int q = blockIdx.x;
  int base = b * SEQ;
  int nq = node[base + q];
  int cq = colid[base + q], tq = tabid[base + q];
  int pq = pad_b[base + q] ? 0 : 1;
  __shared__ int f2pq[8];
  if (threadIdx.x < 8) f2pq[threadIdx.x] = f2p[(size_t)(base + q) * 8 + threadIdx.x];
  __syncthreads();
  for (int k = threadIdx.x; k < SEQ; k += 256) {
    int nk = node[base + k];
    int pk = pad_b[base + k] ? 0 : 1;
    int padok = pq & pk;
    int kv_in = 0, q_in = 0;
#pragma unroll
    for (int t = 0; t < 8; t++) kv_in |= (nk == f2pq[t]);
    const int* fk = &f2p[(size_t)(base + k) * 8];
#pragma unroll
    for (int t = 0; t < 8; t++) q_in |= (nq == fk[t]);
    int feat = ((nq == nk) | kv_in);
    int col = (cq == colid[base + k]) & (tq == tabid[base + k]);
    unsigned char bits = 0;
    if (padok) bits = (unsigned char)((feat ? 1 : 0) | (q_in ? 2 : 0) | (col ? 4 : 0) | 8);
    mb[((size_t)base + q) * SEQ + k] = bits;
  }
}

// ---------------- block reductions / LN ----------------
__device__ __forceinline__ float block_sum256(float v, float* red) {
#pragma unroll
  for (int off = 32; off; off >>= 1) v += __shfl_xor(v, off);
  int w = threadIdx.x >> 6;
  __syncthreads();                      // protect red from previous use
  if ((threadIdx.x & 63) == 0) red[w] = v;
  __syncthreads();
  return red[0] + red[1] + red[2] + red[3];
}

__device__ __forceinline__ float ln256(float y, float* red) {
  float mean = block_sum256(y, red) * (1.0f / 256.0f);
  float dv = y - mean;
  float var = block_sum256(dv * dv, red) * (1.0f / 256.0f);
  return dv * rsqrtf(var + 1e-5f);
}

// ---------------- cell value encoder ----------------
__global__ __launch_bounds__(256) void k_encoder(
    const float* __restrict__ colv, const float* __restrict__ numv,
    const float* __restrict__ textv,
    const float* __restrict__ Wc, const float* __restrict__ bc,
    const float* __restrict__ Wn, const float* __restrict__ bn,
    const float* __restrict__ Wt, const float* __restrict__ bt,
    const float* __restrict__ gc, const float* __restrict__ bec,
    const float* __restrict__ gn, const float* __restrict__ ben,
    const float* __restrict__ gt, const float* __restrict__ bet,
    const float* __restrict__ men, const float* __restrict__ met,
    const unsigned char* __restrict__ pad_b, const unsigned char* __restrict__ msk_b,
    const int* __restrict__ sem, float* __restrict__ x) {
  __shared__ float row[384];
  __shared__ float red[4];
  int token = blockIdx.x, d = threadIdx.x;
  int ispad = pad_b[token];
  float notpad = ispad ? 0.f : 1.f;
  int st = sem[token];
  int mk = msk_b[token];

  for (int i = d; i < 384; i += 256) row[i] = colv[(size_t)token * 384 + i];
  __syncthreads();
  float y = bc[d];
  for (int j = 0; j < 384; j++) y += row[j] * Wc[j * 256 + d];
  float xv = (ln256(y, red) * gc[d] + bec[d]) * notpad;

  // numeric path (cheap: always compute LN, conditionally add)
  {
    float yn = numv[token] * Wn[d] + bn[d];
    float lnv = ln256(yn, red) * gn[d] + ben[d];
    if (st == 0 && !ispad && !mk) xv += lnv;
    if (st == 0 && !ispad && mk)  xv += men[d];
  }
  // text path (expensive: block-uniform condition, skip when unused)
  if (st == 1 && !ispad && !mk) {
    __syncthreads();
    for (int i = d; i < 384; i += 256) row[i] = textv[(size_t)token * 384 + i];
    __syncthreads();
    float yt = bt[d];
    for (int j = 0; j < 384; j++) yt += row[j] * Wt[j * 256 + d];
    xv += ln256(yt, red) * gt[d] + bet[d];
  }
  if (st == 1 && !ispad && mk) xv += met[d];
  x[(size_t)token * 256 + d] = xv;
}

// ---------------- generic LN kernel ----------------
__global__ __launch_bounds__(256) void k_ln(const float* __restrict__ xin,
                                            const float* __restrict__ g,
                                            const float* __restrict__ b,
                                            float* __restrict__ out) {
  __shared__ float red[4];
  int token = blockIdx.x, d = threadIdx.x;
  float v = xin[(size_t)token * 256 + d];
  out[(size_t)token * 256 + d] = ln256(v, red) * g[d] + b[d];
}

__global__ __launch_bounds__(256) void k_ln_out(const float* __restrict__ xin,
                                                const float* __restrict__ g,
                                                const float* __restrict__ b,
                                                void* __restrict__ out,
                                                const int* __restrict__ flags) {
  __shared__ float red[4];
  int token = blockIdx.x, d = threadIdx.x;
  float v = xin[(size_t)token * 256 + d];
  float o = ln256(v, red) * g[d] + b[d];
  size_t idx = (size_t)token * 256 + d;
  if (flags[0]) ((unsigned short*)out)[idx] = f32_to_bf16(o);
  else ((float*)out)[idx] = o;
}

// ---------------- GEMM: C[M,N] (+)= act(A[M,K] @ B[K,N] + bias) ----------------
__device__ __forceinline__ float gelu_tanh(float v) {
  const float c = 0.7978845608028654f; // sqrt(2/pi)
  float t = tanhf(c * (v + 0.044715f * v * v * v));
  return 0.5f * v * (1.f + t);
}

template <int ACT, int ACC>
__global__ __launch_bounds__(256) void k_gemm(
    const float* __restrict__ A, const float* __restrict__ Bm,
    const float* __restrict__ bias, float* __restrict__ C,
    int M, int N, int K) {
  __shared__ float As[16][65];   // [k][m]
  __shared__ float Bs[16][65];   // [k][n]
  int tid = threadIdx.x;
  int bm = blockIdx.y * 64, bn = blockIdx.x * 64;
  int tx = tid & 15, ty = tid >> 4;
  float acc[4][4] = {};
  for (int k0 = 0; k0 < K; k0 += 16) {
    {
      int m = tid >> 2, kk = (tid & 3) * 4;
      float4 av = *(const float4*)&A[(size_t)(bm + m) * K + k0 + kk];
      As[kk + 0][m] = av.x; As[kk + 1][m] = av.y;
      As[kk + 2][m] = av.z; As[kk + 3][m] = av.w;
      int kb = tid >> 4, nn = (tid & 15) * 4;
      float4 bv = *(const float4*)&Bm[(size_t)(k0 + kb) * N + bn + nn];
      Bs[kb][nn + 0] = bv.x; Bs[kb][nn + 1] = bv.y;
      Bs[kb][nn + 2] = bv.z; Bs[kb][nn + 3] = bv.w;
    }
    __syncthreads();
#pragma unroll
    for (int kk = 0; kk < 16; kk++) {
      float a0 = As[kk][ty * 4 + 0], a1 = As[kk][ty * 4 + 1];
      float a2 = As[kk][ty * 4 + 2], a3 = As[kk][ty * 4 + 3];
      float b0 = Bs[kk][tx * 4 + 0], b1 = Bs[kk][tx * 4 + 1];
      float b2 = Bs[kk][tx * 4 + 2], b3 = Bs[kk][tx * 4 + 3];
      acc[0][0] += a0 * b0; acc[0][1] += a0 * b1; acc[0][2] += a0 * b2; acc[0][3] += a0 * b3;
      acc[1][0] += a1 * b0; acc[1][1] += a1 * b1; acc[1][2] += a1 * b2; acc[1][3] += a1 * b3;
      acc[2][0] += a2 * b0; acc[2][1] += a2 * b1; acc[2][2] += a2 * b2; acc[2][3] += a2 * b3;
      acc[3][0] += a3 * b0; acc[3][1] += a3 * b1; acc[3][2] += a3 * b2; acc[3][3] += a3 * b3;
    }
    __syncthreads();
  }
#pragma unroll
  for (int i = 0; i < 4; i++) {
#pragma unroll
    for (int j = 0; j < 4; j++) {
      int n = bn + tx * 4 + j;
      float v = acc[i][j];
      if (bias) v += bias[n];
      if (ACT) v = gelu_tanh(v);
      size_t idx = (size_t)(bm + ty * 4 + i) * N + n;
      if (ACC) C[idx] += v; else C[idx] = v;
    }
  }
}

// ---------------- MFMA masked flash attention ----------------
// QKV: f32 [2048][3072], col = l*768 + {0:q,256:k,512:v} + h*32 + dh
// Ocat: f32 [2048][1024], col = l*256 + h*32 + dh
// grid: (S/64, H, B*4), block: 256 (4 waves); wave w owns q-rows [qblk+16w, +16)
// Fragment layout (16x16x32 bf16): A: lane l -> row l%16, k = 8*(l/16)+j
//                                  B: lane l -> col l%16, k = 8*(l/16)+j
//                                  D: lane l -> col l%16, row = 4*(l/16)+reg
__global__ __launch_bounds__(256) void k_attn_mfma(
    const float* __restrict__ QKV, const unsigned char* __restrict__ mb,
    float* __restrict__ Ocat) {
  __shared__ __align__(16) unsigned short Ks[64][40];    // [key][dh], pitch 40
  __shared__ __align__(16) unsigned short Vt[32][72];    // [dh][key], pitch 72
  __shared__ __align__(16) unsigned short Pl[4][16][72]; // per-wave P [q][key]
  __shared__ __align__(16) unsigned char  Ml[64][64];    // [q in block][key in chunk]

  int tid = threadIdx.x;
  int wave = tid >> 6, lane = tid & 63;
  int g = lane >> 4, c = lane & 15;
  int qblk = blockIdx.x * 64;
  int h = blockIdx.y;
  int b = blockIdx.z >> 2, l = blockIdx.z & 3;
  size_t tokbase = (size_t)b * SEQ;
  int qcol = l * 768 + h * 32;
  int kcol = qcol + 256, vcol = qcol + 512;

  // Q fragment (scaled by 1/sqrt(32))
  short8 qf;
  {
    const float* qp = &QKV[(tokbase + qblk + wave * 16 + c) * 3072 + qcol + g * 8];
    float4 a = *(const float4*)qp, bq = *(const float4*)(qp + 4);
    const float sc = 0.17677669529663687f;
    a.x *= sc; a.y *= sc; a.z *= sc; a.w *= sc;
    bq.x *= sc; bq.y *= sc; bq.z *= sc; bq.w *= sc;
    qf = cvt8(a, bq);
  }

  f32x4 zero = {0.f, 0.f, 0.f, 0.f};
  f32x4 oacc0 = zero, oacc1 = zero;
  float m[4] = {-1e30f, -1e30f, -1e30f, -1e30f};
  float ls[4] = {0.f, 0.f, 0.f, 0.f};
  int okany[4] = {0, 0, 0, 0};

  int skey = tid >> 2, sd = (tid & 3) * 8;   // staging: thread -> (key, 8 dims)

  for (int kc = 0; kc < SEQ; kc += 64) {
    __syncthreads();
    // ---- stage K (row-major bf16), V (transposed bf16), mask tile ----
    {
      const float* kp = &QKV[(tokbase + kc + skey) * 3072 + kcol + sd];
      float4 ka = *(const float4*)kp, kb4 = *(const float4*)(kp + 4);
      *(short8*)&Ks[skey][sd] = cvt8(ka, kb4);
      const float* vp = &QKV[(tokbase + kc + skey) * 3072 + vcol + sd];
      float4 va = *(const float4*)vp, vb4 = *(const float4*)(vp + 4);
      float vv[8] = {va.x, va.y, va.z, va.w, vb4.x, vb4.y, vb4.z, vb4.w};
#pragma unroll
      for (int j = 0; j < 8; j++) Vt[sd + j][skey] = f32_to_bf16(vv[j]);
      int mrow = tid >> 2, mseg = tid & 3;
      *(uint4*)&Ml[mrow][mseg * 16] =
          *(const uint4*)&mb[(tokbase + qblk + mrow) * SEQ + kc + mseg * 16];
    }
    __syncthreads();

    // ---- QK^T: 4 MFMAs -> S[16q][64k] in D-layout ----
    f32x4 sa[4];
#pragma unroll
    for (int t = 0; t < 4; t++) {
      short8 kb = *(short8*)&Ks[t * 16 + c][g * 8];
      sa[t] = __builtin_amdgcn_mfma_f32_16x16x32_bf16(qf, kb, zero, 0, 0, 0);
    }

    // ---- mask + online softmax (rows r = 4*g+reg, all lanes active) ----
#pragma unroll
    for (int r = 0; r < 4; r++) {
      float sv[4];
      float cm = -1e30f;
#pragma unroll
      for (int t = 0; t < 4; t++) {
        int ok = (Ml[wave * 16 + g * 4 + r][t * 16 + c] >> l) & 1;
        okany[r] |= ok;
        sv[t] = ok ? sa[t][r] : NEGV;
        cm = fmaxf(cm, sv[t]);
      }
#pragma unroll
      for (int off = 1; off < 16; off <<= 1) cm = fmaxf(cm, __shfl_xor(cm, off));
      float mn = fmaxf(m[r], cm);
      float scale = __expf(m[r] - mn);
      float psum = 0.f;
      float pv[4];
#pragma unroll
      for (int t = 0; t < 4; t++) { pv[t] = __expf(sv[t] - mn); psum += pv[t]; }
#pragma unroll
      for (int off = 1; off < 16; off <<= 1) psum += __shfl_xor(psum, off);
      ls[r] = ls[r] * scale + psum;
      m[r] = mn;
      oacc0[r] *= scale;
      oacc1[r] *= scale;
#pragma unroll
      for (int t = 0; t < 4; t++)
        Pl[wave][g * 4 + r][t * 16 + c] = f32_to_bf16(pv[t]);
    }

    // ---- PV: O[16q][32d] += P[16][64] @ V[64][32] (4 MFMAs) ----
#pragma unroll
    for (int k2 = 0; k2 < 2; k2++) {
      short8 pa = *(short8*)&Pl[wave][c][k2 * 32 + g * 8];
      short8 v0 = *(short8*)&Vt[c][k2 * 32 + g * 8];
      short8 v1 = *(short8*)&Vt[16 + c][k2 * 32 + g * 8];
      oacc0 = __builtin_amdgcn_mfma_f32_16x16x32_bf16(pa, v0, oacc0, 0, 0, 0);
      oacc1 = __builtin_amdgcn_mfma_f32_16x16x32_bf16(pa, v1, oacc1, 0, 0, 0);
    }
  }

  // ---- epilogue: rowany reduce, normalize, store ----
#pragma unroll
  for (int r = 0; r < 4; r++) {
    int o = okany[r];
#pragma unroll
    for (int off = 1; off < 16; off <<= 1) o |= __shfl_xor(o, off);
    okany[r] = o;
  }
#pragma unroll
  for (int r = 0; r < 4; r++) {
    float inv = okany[r] ? (1.f / ls[r]) : 0.f;
    size_t row = tokbase + qblk + wave * 16 + g * 4 + r;
    float* op = &Ocat[row * 1024 + l * 256 + h * 32];
    op[c] = oacc0[r] * inv;
    op[16 + c] = oacc1[r] * inv;
  }
}

// ---------------- host ----------------
extern "C" void kernel_launch(void* const* d_in, const int* in_sizes, int n_in,
                              void* d_out, int out_size, void* d_ws, size_t ws_size,
                              hipStream_t stream) {
  (void)n_in; (void)out_size; (void)ws_size;
  char* wsb = (char*)d_ws;
  int* flags = (int*)wsb;
  unsigned char* pad_b = (unsigned char*)(wsb + 256);
  unsigned char* msk_b = (unsigned char*)(wsb + 256 + 2048);
  unsigned char* mbits = (unsigned char*)(wsb + 8192);            // 2 MB
  float* fbase = (float*)(wsb + 8192 + 2 * 1024 * 1024);
  size_t fo = 0;
  auto alloc = [&](size_t n) { float* p = fbase + fo; fo += (n + 63) & ~(size_t)63; return p; };

  float* Wc = alloc(98304);  float* bc = alloc(256);
  float* Wn = alloc(256);    float* bn = alloc(256);
  float* Wt = alloc(98304);  float* bt = alloc(256);
  float* gc = alloc(256);    float* bec = alloc(256);
  float* gn = alloc(256);    float* ben = alloc(256);
  float* gt = alloc(256);    float* bet = alloc(256);
  float* men = alloc(256);   float* met = alloc(256);
  float* Wqkv = alloc(2 * 786432);
  float* Woc = alloc(524288);
  float* l1g = alloc(512);   float* l1b = alloc(512);
  float* l2g = alloc(512);   float* l2b = alloc(512);
  float* W1c = alloc(524288); float* b1c = alloc(2048);
  float* W2c = alloc(524288); float* b2c = alloc(512);
  float* goc = alloc(256);   float* beo = alloc(256);
  float* colv = alloc(786432); float* numv = alloc(2048); float* textv = alloc(786432);
  float* x = alloc(524288);
  float* h = alloc(524288);
  float* Ocat = alloc(2097152);
  float* QKV = alloc(6291456);
  float* fbuf = QKV;  // FFN hidden aliases QKV (QKV dead by then)

  k_detect<<<1, 64, 0, stream>>>(d_in[7], d_in[6], flags);
  k_convert_bools<<<8, 256, 0, stream>>>(d_in[4], d_in[6], pad_b, msk_b, flags);

  ConvArgs ca;
  const int idxs[28] = {10, 11, 12, 13, 14, 15, 16, 17, 18, 19, 20, 21, 22, 23,
                        27, 28, 29, 30, 31, 32, 33, 34, 35, 36, 37, 7, 8, 9};
  float* dsts[28] = {Wc, bc, Wn, bn, Wt, bt, gc, bec, gn, ben, gt, bet, men, met,
                     Woc, l1g, l1b, l2g, l2b, W1c, b1c, W2c, b2c, goc, beo,
                     colv, numv, textv};
  for (int t = 0; t < 28; t++) {
    ca.e[t].src = d_in[idxs[t]];
    ca.e[t].dst = dsts[t];
    ca.e[t].n = in_sizes[idxs[t]];
  }
  k_convert_many<<<dim3(64, 28), 256, 0, stream>>>(ca, flags);
  k_convert_qkv<<<(2 * 256 * 3072 + 255) / 256, 256, 0, stream>>>(
      d_in[24], d_in[25], d_in[26], Wqkv, flags);
  k_masks<<<dim3(1024, 2), 256, 0, stream>>>(
      (const int*)d_in[0], (const int*)d_in[1], (const int*)d_in[2],
      (const int*)d_in[3], pad_b, mbits);
  k_encoder<<<2048, 256, 0, stream>>>(colv, numv, textv, Wc, bc, Wn, bn, Wt, bt,
                                      gc, bec, gn, ben, gt, bet, men, met,
                                      pad_b, msk_b, (const int*)d_in[5], x);
  for (int i = 0; i < 2; i++) {
    k_ln<<<2048, 256, 0, stream>>>(x, l1g + i * 256, l1b + i * 256, h);
    k_gemm<0, 0><<<dim3(48, 32), 256, 0, stream>>>(h, Wqkv + (size_t)i * 786432,
                                                   nullptr, QKV, 2048, 3072, 256);
    k_attn_mfma<<<dim3(16, 8, 8), 256, 0, stream>>>(QKV, mbits, Ocat);
    k_gemm<0, 1><<<dim3(4, 32), 256, 0, stream>>>(Ocat, Woc + (size_t)i * 262144,
                                                  nullptr, x, 2048, 256, 1024);
    k_ln<<<2048, 256, 0, stream>>>(x, l2g + i * 256, l2b + i * 256, h);
    k_gemm<1, 0><<<dim3(16, 32), 256, 0, stream>>>(h, W1c + (size_t)i * 262144,
                                                   b1c + (size_t)i * 1024, fbuf,
                                                   2048, 1024, 256);
    k_gemm<0, 1><<<dim3(4, 32), 256, 0, stream>>>(fbuf, W2c + (size_t)i * 262144,
                                                  b2c + (size_t)i * 256, x,
                                                  2048, 256, 1024);
  }
  k_ln_out<<<2048, 256, 0, stream>>>(x, goc, beo, d_out, flags);
}

// Round 3
// 385.176 us; speedup vs baseline: 8.1258x; 1.9146x over previous
//
#include <hip/hip_runtime.h>
#include <stdint.h>

#define TOKS 2048
#define SEQ 1024
#define NEGV -1e9f

typedef __attribute__((ext_vector_type(8))) short short8;
typedef __attribute__((ext_vector_type(4))) float f32x4;

// ---------------- dtype helpers ----------------
__device__ __forceinline__ float loadf(const void* p, size_t i, int isbf16) {
  if (isbf16) {
    unsigned short u = ((const unsigned short*)p)[i];
    return __uint_as_float(((unsigned)u) << 16);
  }
  return ((const float*)p)[i];
}
__device__ __forceinline__ unsigned short f32_to_bf16(float f) {
  unsigned u = __float_as_uint(f);
  unsigned r = u + 0x7FFFu + ((u >> 16) & 1u);
  return (unsigned short)(r >> 16);
}
__device__ __forceinline__ float bf2f(unsigned short u) {
  return __uint_as_float(((unsigned)u) << 16);
}

// ---------------- detection ----------------
__global__ void k_detect(const void* fs, const void* bs, int* flags) {
  int lane = threadIdx.x;
  int bad = 0;
  for (int i = lane; i < 256; i += 64) {
    unsigned short u = ((const unsigned short*)fs)[i];
    float v = __uint_as_float(((unsigned)u) << 16);
    if (!(fabsf(v) <= 100.f)) bad = 1;
  }
  int big = 0;
  for (int i = lane; i < 512; i += 64) {
    if (((const unsigned*)bs)[i] > 1u) big = 1;
  }
#pragma unroll
  for (int off = 32; off; off >>= 1) {
    bad |= __shfl_xor(bad, off);
    big |= __shfl_xor(big, off);
  }
  if (lane == 0) { flags[0] = bad ? 0 : 1; flags[1] = big ? 1 : 0; }
}

// ---------------- plain f32 canonicalization ----------------
struct ConvEntry { const void* src; float* dst; int n; };
struct ConvArgs { ConvEntry e[25]; };

__global__ void k_convert_many(ConvArgs ca, const int* __restrict__ flags) {
  int isbf = flags[0];
  ConvEntry E = ca.e[blockIdx.y];
  for (int i = blockIdx.x * 256 + threadIdx.x; i < E.n; i += gridDim.x * 256)
    E.dst[i] = loadf(E.src, (size_t)i, isbf);
}

__global__ void k_convert_bools(const void* pad, const void* msk,
                                unsigned char* pb, unsigned char* mb,
                                const int* __restrict__ flags) {
  int isb = flags[1];
  int i = blockIdx.x * 256 + threadIdx.x;
  if (i < TOKS) {
    if (isb) {
      pb[i] = ((const unsigned char*)pad)[i] ? 1 : 0;
      mb[i] = ((const unsigned char*)msk)[i] ? 1 : 0;
    } else {
      pb[i] = (((const int*)pad)[i] != 0) ? 1 : 0;
      mb[i] = (((const int*)msk)[i] != 0) ? 1 : 0;
    }
  }
}

// ---------------- transposed bf16 weight conversion ----------------
// dst[n*pitch + k] = bf16(src[soff + k*N + n]),  k<K, n<N
struct TEntry { const void* src; unsigned short* dst; int soff, K, N, pitch; };
struct TArgs { TEntry e[36]; };

__global__ __launch_bounds__(256) void k_conv_T(TArgs ta, const int* __restrict__ flags) {
  int isbf = flags[0];
  TEntry E = ta.e[blockIdx.y];
  int ktiles = E.K >> 5, ntiles = E.N >> 5;
  if ((int)blockIdx.x >= ktiles * ntiles) return;
  int tk = blockIdx.x % ktiles, tn = blockIdx.x / ktiles;
  __shared__ float t[32][33];
  int tx = threadIdx.x & 31, ty = threadIdx.x >> 5;  // 32 x 8
#pragma unroll
  for (int s = 0; s < 4; s++) {
    int k = tk * 32 + ty + s * 8, n = tn * 32 + tx;
    t[ty + s * 8][tx] = loadf(E.src, (size_t)E.soff + (size_t)k * E.N + n, isbf);
  }
  __syncthreads();
#pragma unroll
  for (int s = 0; s < 4; s++) {
    int n = tn * 32 + ty + s * 8, k = tk * 32 + tx;
    E.dst[(size_t)n * E.pitch + k] = f32_to_bf16(t[tx][ty + s * 8]);
  }
}

// ---------------- pairwise mask bits ----------------
__global__ __launch_bounds__(256) void k_masks(
    const int* __restrict__ node, const int* __restrict__ f2p,
    const int* __restrict__ colid, const int* __restrict__ tabid,
    const unsigned char* __restrict__ pad_b, unsigned char* __restrict__ mb) {
  int b = blockIdx.y;
  int q = blockIdx.x;
  int base = b * SEQ;
  int nq = node[base + q];
  int cq = colid[base + q], tq = tabid[base + q];
  int pq = pad_b[base + q] ? 0 : 1;
  __shared__ int f2pq[8];
  if (threadIdx.x < 8) f2pq[threadIdx.x] = f2p[(size_t)(base + q) * 8 + threadIdx.x];
  __syncthreads();
  for (int k = threadIdx.x; k < SEQ; k += 256) {
    int nk = node[base + k];
    int pk = pad_b[base + k] ? 0 : 1;
    int padok = pq & pk;
    int kv_in = 0, q_in = 0;
#pragma unroll
    for (int t = 0; t < 8; t++) kv_in |= (nk == f2pq[t]);
    const int* fk = &f2p[(size_t)(base + k) * 8];
#pragma unroll
    for (int t = 0; t < 8; t++) q_in |= (nq == fk[t]);
    int feat = ((nq == nk) | kv_in);
    int col = (cq == colid[base + k]) & (tq == tabid[base + k]);
    unsigned char bits = 0;
    if (padok) bits = (unsigned char)((feat ? 1 : 0) | (q_in ? 2 : 0) | (col ? 4 : 0) | 8);
    mb[((size_t)base + q) * SEQ + k] = bits;
  }
}

// ---------------- block reductions / LN ----------------
__device__ __forceinline__ float block_sum256(float v, float* red) {
#pragma unroll
  for (int off = 32; off; off >>= 1) v += __shfl_xor(v, off);
  int w = threadIdx.x >> 6;
  __syncthreads();
  if ((threadIdx.x & 63) == 0) red[w] = v;
  __syncthreads();
  return red[0] + red[1] + red[2] + red[3];
}
__device__ __forceinline__ float ln256(float y, float* red) {
  float mean = block_sum256(y, red) * (1.0f / 256.0f);
  float dv = y - mean;
  float var = block_sum256(dv * dv, red) * (1.0f / 256.0f);
  return dv * rsqrtf(var + 1e-5f);
}

// ---------------- cell value encoder ----------------
__global__ __launch_bounds__(256) void k_encoder(
    const float* __restrict__ colv, const float* __restrict__ numv,
    const float* __restrict__ textv,
    const float* __restrict__ Wc, const float* __restrict__ bc,
    const float* __restrict__ Wn, const float* __restrict__ bn,
    const float* __restrict__ Wt, const float* __restrict__ bt,
    const float* __restrict__ gc, const float* __restrict__ bec,
    const float* __restrict__ gn, const float* __restrict__ ben,
    const float* __restrict__ gt, const float* __restrict__ bet,
    const float* __restrict__ men, const float* __restrict__ met,
    const unsigned char* __restrict__ pad_b, const unsigned char* __restrict__ msk_b,
    const int* __restrict__ sem, float* __restrict__ x) {
  __shared__ float row[384];
  __shared__ float red[4];
  int token = blockIdx.x, d = threadIdx.x;
  int ispad = pad_b[token];
  float notpad = ispad ? 0.f : 1.f;
  int st = sem[token];
  int mk = msk_b[token];

  for (int i = d; i < 384; i += 256) row[i] = colv[(size_t)token * 384 + i];
  __syncthreads();
  float y = bc[d];
  for (int j = 0; j < 384; j++) y += row[j] * Wc[j * 256 + d];
  float xv = (ln256(y, red) * gc[d] + bec[d]) * notpad;

  {
    float yn = numv[token] * Wn[d] + bn[d];
    float lnv = ln256(yn, red) * gn[d] + ben[d];
    if (st == 0 && !ispad && !mk) xv += lnv;
    if (st == 0 && !ispad && mk)  xv += men[d];
  }
  if (st == 1 && !ispad && !mk) {
    __syncthreads();
    for (int i = d; i < 384; i += 256) row[i] = textv[(size_t)token * 384 + i];
    __syncthreads();
    float yt = bt[d];
    for (int j = 0; j < 384; j++) yt += row[j] * Wt[j * 256 + d];
    xv += ln256(yt, red) * gt[d] + bet[d];
  }
  if (st == 1 && !ispad && mk) xv += met[d];
  x[(size_t)token * 256 + d] = xv;
}

// ---------------- LN kernels ----------------
__global__ __launch_bounds__(256) void k_ln_bf(const float* __restrict__ xin,
                                               const float* __restrict__ g,
                                               const float* __restrict__ b,
                                               unsigned short* __restrict__ out) {
  __shared__ float red[4];
  int token = blockIdx.x, d = threadIdx.x;
  float v = xin[(size_t)token * 256 + d];
  out[(size_t)token * 256 + d] = f32_to_bf16(ln256(v, red) * g[d] + b[d]);
}

__global__ __launch_bounds__(256) void k_ln_out(const float* __restrict__ xin,
                                                const float* __restrict__ g,
                                                const float* __restrict__ b,
                                                void* __restrict__ out,
                                                const int* __restrict__ flags) {
  __shared__ float red[4];
  int token = blockIdx.x, d = threadIdx.x;
  float v = xin[(size_t)token * 256 + d];
  float o = ln256(v, red) * g[d] + b[d];
  size_t idx = (size_t)token * 256 + d;
  if (flags[0]) ((unsigned short*)out)[idx] = f32_to_bf16(o);
  else ((float*)out)[idx] = o;
}

// ---------------- bf16 MFMA GEMM ----------------
// C[M,N] (+)= act(A[M,K] @ Bt[N,K]^T + bias)
// A, Bt bf16 row-major; 4 waves in 2x2; frag layout per 16x16x32 bf16 MFMA.
__device__ __forceinline__ float gelu_tanh(float v) {
  const float c = 0.7978845608028654f;
  float t = tanhf(c * (v + 0.044715f * v * v * v));
  return 0.5f * v * (1.f + t);
}

template <int BM, int BN, int ACT, int ACC, int OUTBF>
__global__ __launch_bounds__(256) void k_gemm_bf(
    const unsigned short* __restrict__ A, const unsigned short* __restrict__ Bt,
    const float* __restrict__ bias, void* __restrict__ Cv,
    int M, int N, int K) {
  __shared__ __align__(16) unsigned short As[BM][40];
  __shared__ __align__(16) unsigned short Bs[BN][40];
  constexpr int FI = BM / 32, FJ = BN / 32;
  int tid = threadIdx.x, wave = tid >> 6, lane = tid & 63;
  int g = lane >> 4, c = lane & 15;
  int wr = wave >> 1, wc = wave & 1;
  int bm = blockIdx.y * BM, bn = blockIdx.x * BN;
  f32x4 acc[FI][FJ] = {};
  int sr = tid >> 2, ss = (tid & 3) * 8;

  for (int k0 = 0; k0 < K; k0 += 32) {
    __syncthreads();
#pragma unroll
    for (int rr = 0; rr < BM; rr += 64)
      *(short8*)&As[rr + sr][ss] = *(const short8*)&A[(size_t)(bm + rr + sr) * K + k0 + ss];
#pragma unroll
    for (int rr = 0; rr < BN; rr += 64)
      *(short8*)&Bs[rr + sr][ss] = *(const short8*)&Bt[(size_t)(bn + rr + sr) * K + k0 + ss];
    __syncthreads();
    short8 af[FI], bf[FJ];
#pragma unroll
    for (int i = 0; i < FI; i++) af[i] = *(short8*)&As[wr * (BM / 2) + i * 16 + c][g * 8];
#pragma unroll
    for (int j = 0; j < FJ; j++) bf[j] = *(short8*)&Bs[wc * (BN / 2) + j * 16 + c][g * 8];
#pragma unroll
    for (int i = 0; i < FI; i++)
#pragma unroll
      for (int j = 0; j < FJ; j++)
        acc[i][j] = __builtin_amdgcn_mfma_f32_16x16x32_bf16(af[i], bf[j], acc[i][j], 0, 0, 0);
  }
#pragma unroll
  for (int i = 0; i < FI; i++)
#pragma unroll
    for (int j = 0; j < FJ; j++)
#pragma unroll
      for (int r = 0; r < 4; r++) {
        int row = bm + wr * (BM / 2) + i * 16 + g * 4 + r;
        int col = bn + wc * (BN / 2) + j * 16 + c;
        float v = acc[i][j][r];
        if (bias) v += bias[col];
        if (ACT) v = gelu_tanh(v);
        size_t idx = (size_t)row * N + col;
        if (ACC) ((float*)Cv)[idx] += v;
        else if (OUTBF) ((unsigned short*)Cv)[idx] = f32_to_bf16(v);
        else ((float*)Cv)[idx] = v;
      }
}

// ---------------- MFMA masked flash attention (bf16 QKV) ----------------
// QKVb: bf16 [2048][3072], col = l*768 + {0:q,256:k,512:v} + h*32 + dh
// Ocat: bf16 [2048][1024]
// flat grid 1024: z=bid&7 -> (b,l) [XCD-local], y=(bid>>3)&7 -> h, x=bid>>6 -> qblk
__global__ __launch_bounds__(256) void k_attn_mfma(
    const unsigned short* __restrict__ QKVb, const unsigned char* __restrict__ mb,
    unsigned short* __restrict__ Ocat) {
  __shared__ __align__(16) unsigned short Ks[64][40];
  __shared__ __align__(16) unsigned short Vt[32][72];
  __shared__ __align__(16) unsigned short Pl[4][16][72];
  __shared__ __align__(16) unsigned char  Ml[64][80];   // pitch 80 (16|80, odd*4 banks)

  int bid = blockIdx.x;
  int z = bid & 7, h = (bid >> 3) & 7, qi = bid >> 6;
  int b = z >> 2, l = z & 3;
  int tid = threadIdx.x;
  int wave = tid >> 6, lane = tid & 63;
  int g = lane >> 4, c = lane & 15;
  int qblk = qi * 64;
  size_t tokbase = (size_t)b * SEQ;
  int qcol = l * 768 + h * 32;
  int kcol = qcol + 256, vcol = qcol + 512;

  // Q fragment, scaled by 1/sqrt(32)
  short8 qf;
  {
    short8 qraw = *(const short8*)&QKVb[(tokbase + qblk + wave * 16 + c) * 3072 + qcol + g * 8];
    const float sc = 0.17677669529663687f;
#pragma unroll
    for (int j = 0; j < 8; j++)
      qf[j] = (short)f32_to_bf16(bf2f((unsigned short)qraw[j]) * sc);
  }

  f32x4 zero = {0.f, 0.f, 0.f, 0.f};
  f32x4 oacc0 = zero, oacc1 = zero;
  float m[4] = {-1e30f, -1e30f, -1e30f, -1e30f};
  float ls[4] = {0.f, 0.f, 0.f, 0.f};
  int okany[4] = {0, 0, 0, 0};

  int skey = tid >> 2, sd = (tid & 3) * 8;

  for (int kc = 0; kc < SEQ; kc += 64) {
    __syncthreads();
    {
      *(short8*)&Ks[skey][sd] =
          *(const short8*)&QKVb[(tokbase + kc + skey) * 3072 + kcol + sd];
      short8 vv = *(const short8*)&QKVb[(tokbase + kc + skey) * 3072 + vcol + sd];
#pragma unroll
      for (int j = 0; j < 8; j++) Vt[sd + j][skey] = (unsigned short)vv[j];
      int mrow = tid >> 2, mseg = tid & 3;
      *(uint4*)&Ml[mrow][mseg * 16] =
          *(const uint4*)&mb[(tokbase + qblk + mrow) * SEQ + kc + mseg * 16];
    }
    __syncthreads();

    // QK^T
    f32x4 sa[4];
#pragma unroll
    for (int t = 0; t < 4; t++) {
      short8 kb = *(short8*)&Ks[t * 16 + c][g * 8];
      sa[t] = __builtin_amdgcn_mfma_f32_16x16x32_bf16(qf, kb, zero, 0, 0, 0);
    }

    // mask + online softmax (rows 4g+r)
#pragma unroll
    for (int r = 0; r < 4; r++) {
      float sv[4];
      float cm = -1e30f;
#pragma unroll
      for (int t = 0; t < 4; t++) {
        int ok = (Ml[wave * 16 + g * 4 + r][t * 16 + c] >> l) & 1;
        okany[r] |= ok;
        sv[t] = ok ? sa[t][r] : NEGV;
        cm = fmaxf(cm, sv[t]);
      }
#pragma unroll
      for (int off = 1; off < 16; off <<= 1) cm = fmaxf(cm, __shfl_xor(cm, off));
      float mn = fmaxf(m[r], cm);
      float scale = __expf(m[r] - mn);
      float psum = 0.f;
      float pv[4];
#pragma unroll
      for (int t = 0; t < 4; t++) { pv[t] = __expf(sv[t] - mn); psum += pv[t]; }
#pragma unroll
      for (int off = 1; off < 16; off <<= 1) psum += __shfl_xor(psum, off);
      ls[r] = ls[r] * scale + psum;
      m[r] = mn;
      oacc0[r] *= scale;
      oacc1[r] *= scale;
#pragma unroll
      for (int t = 0; t < 4; t++)
        Pl[wave][g * 4 + r][t * 16 + c] = f32_to_bf16(pv[t]);
    }

    // PV
#pragma unroll
    for (int k2 = 0; k2 < 2; k2++) {
      short8 pa = *(short8*)&Pl[wave][c][k2 * 32 + g * 8];
      short8 v0 = *(short8*)&Vt[c][k2 * 32 + g * 8];
      short8 v1 = *(short8*)&Vt[16 + c][k2 * 32 + g * 8];
      oacc0 = __builtin_amdgcn_mfma_f32_16x16x32_bf16(pa, v0, oacc0, 0, 0, 0);
      oacc1 = __builtin_amdgcn_mfma_f32_16x16x32_bf16(pa, v1, oacc1, 0, 0, 0);
    }
  }

#pragma unroll
  for (int r = 0; r < 4; r++) {
    int o = okany[r];
#pragma unroll
    for (int off = 1; off < 16; off <<= 1) o |= __shfl_xor(o, off);
    okany[r] = o;
  }
#pragma unroll
  for (int r = 0; r < 4; r++) {
    float inv = okany[r] ? (1.f / ls[r]) : 0.f;
    size_t row = tokbase + qblk + wave * 16 + g * 4 + r;
    unsigned short* op = &Ocat[row * 1024 + l * 256 + h * 32];
    op[c] = f32_to_bf16(oacc0[r] * inv);
    op[16 + c] = f32_to_bf16(oacc1[r] * inv);
  }
}

// ---------------- host ----------------
extern "C" void kernel_launch(void* const* d_in, const int* in_sizes, int n_in,
                              void* d_out, int out_size, void* d_ws, size_t ws_size,
                              hipStream_t stream) {
  (void)n_in; (void)out_size; (void)ws_size;
  char* wsb = (char*)d_ws;
  int* flags = (int*)wsb;
  unsigned char* pad_b = (unsigned char*)(wsb + 256);
  unsigned char* msk_b = (unsigned char*)(wsb + 256 + 2048);
  unsigned char* mbits = (unsigned char*)(wsb + 8192);            // 2 MB
  float* fbase = (float*)(wsb + 8192 + 2 * 1024 * 1024);
  size_t fo = 0;
  auto alloc = [&](size_t n) { float* p = fbase + fo; fo += (n + 63) & ~(size_t)63; return p; };

  // f32 params
  float* Wc = alloc(98304);  float* bc = alloc(256);
  float* Wn = alloc(256);    float* bn = alloc(256);
  float* Wt = alloc(98304);  float* bt = alloc(256);
  float* gc = alloc(256);    float* bec = alloc(256);
  float* gn = alloc(256);    float* ben = alloc(256);
  float* gt = alloc(256);    float* bet = alloc(256);
  float* men = alloc(256);   float* met = alloc(256);
  float* l1g = alloc(512);   float* l1b = alloc(512);
  float* l2g = alloc(512);   float* l2b = alloc(512);
  float* b1c = alloc(2048);  float* b2c = alloc(512);
  float* goc = alloc(256);   float* beo = alloc(256);
  float* colv = alloc(786432); float* numv = alloc(2048); float* textv = alloc(786432);
  float* x = alloc(524288);
  // bf16 buffers (allocated in f32 units, reinterpreted)
  unsigned short* h     = (unsigned short*)alloc(262144);   // 2048x256
  unsigned short* WqkvT = (unsigned short*)alloc(786432);   // 2 x 3072 x 256
  unsigned short* WoT   = (unsigned short*)alloc(262144);   // 2 x 256 x 1024
  unsigned short* W1T   = (unsigned short*)alloc(262144);   // 2 x 1024 x 256
  unsigned short* W2T   = (unsigned short*)alloc(262144);   // 2 x 256 x 1024
  unsigned short* QKVb  = (unsigned short*)alloc(3145728);  // 2048x3072 bf16
  unsigned short* Ocat  = (unsigned short*)alloc(1048576);  // 2048x1024 bf16
  unsigned short* fbuf  = QKVb;                             // FFN hidden aliases QKV

  k_detect<<<1, 64, 0, stream>>>(d_in[7], d_in[6], flags);
  k_convert_bools<<<8, 256, 0, stream>>>(d_in[4], d_in[6], pad_b, msk_b, flags);

  ConvArgs ca;
  const int idxs[25] = {10, 11, 12, 13, 14, 15, 16, 17, 18, 19, 20, 21, 22, 23,
                        28, 29, 30, 31, 33, 35, 36, 37, 7, 8, 9};
  float* dsts[25] = {Wc, bc, Wn, bn, Wt, bt, gc, bec, gn, ben, gt, bet, men, met,
                     l1g, l1b, l2g, l2b, b1c, b2c, goc, beo, colv, numv, textv};
  for (int t = 0; t < 25; t++) {
    ca.e[t].src = d_in[idxs[t]];
    ca.e[t].dst = dsts[t];
    ca.e[t].n = in_sizes[idxs[t]];
  }
  k_convert_many<<<dim3(64, 25), 256, 0, stream>>>(ca, flags);

  // transposed bf16 weights
  TArgs ta;
  int ne = 0;
  for (int i = 0; i < 2; i++)
    for (int l = 0; l < 4; l++)
      for (int w = 0; w < 3; w++) {
        ta.e[ne].src = d_in[24 + w];
        ta.e[ne].soff = (i * 4 + l) * 65536;
        ta.e[ne].dst = WqkvT + (size_t)i * 786432 + (size_t)(l * 768 + w * 256) * 256;
        ta.e[ne].K = 256; ta.e[ne].N = 256; ta.e[ne].pitch = 256;
        ne++;
      }
  for (int i = 0; i < 2; i++)
    for (int l = 0; l < 4; l++) {
      ta.e[ne].src = d_in[27];
      ta.e[ne].soff = (i * 4 + l) * 65536;
      ta.e[ne].dst = WoT + (size_t)i * 262144 + l * 256;
      ta.e[ne].K = 256; ta.e[ne].N = 256; ta.e[ne].pitch = 1024;
      ne++;
    }
  for (int i = 0; i < 2; i++) {
    ta.e[ne].src = d_in[32];
    ta.e[ne].soff = i * 262144;
    ta.e[ne].dst = W1T + (size_t)i * 262144;
    ta.e[ne].K = 256; ta.e[ne].N = 1024; ta.e[ne].pitch = 256;
    ne++;
  }
  for (int i = 0; i < 2; i++) {
    ta.e[ne].src = d_in[34];
    ta.e[ne].soff = i * 262144;
    ta.e[ne].dst = W2T + (size_t)i * 262144;
    ta.e[ne].K = 1024; ta.e[ne].N = 256; ta.e[ne].pitch = 1024;
    ne++;
  }
  k_conv_T<<<dim3(256, 36), 256, 0, stream>>>(ta, flags);

  k_masks<<<dim3(1024, 2), 256, 0, stream>>>(
      (const int*)d_in[0], (const int*)d_in[1], (const int*)d_in[2],
      (const int*)d_in[3], pad_b, mbits);
  k_encoder<<<2048, 256, 0, stream>>>(colv, numv, textv, Wc, bc, Wn, bn, Wt, bt,
                                      gc, bec, gn, ben, gt, bet, men, met,
                                      pad_b, msk_b, (const int*)d_in[5], x);
  for (int i = 0; i < 2; i++) {
    k_ln_bf<<<2048, 256, 0, stream>>>(x, l1g + i * 256, l1b + i * 256, h);
    k_gemm_bf<128, 128, 0, 0, 1><<<dim3(24, 16), 256, 0, stream>>>(
        h, WqkvT + (size_t)i * 786432, nullptr, QKVb, 2048, 3072, 256);
    k_attn_mfma<<<1024, 256, 0, stream>>>(QKVb, mbits, Ocat);
    k_gemm_bf<64, 64, 0, 1, 0><<<dim3(4, 32), 256, 0, stream>>>(
        Ocat, WoT + (size_t)i * 262144, nullptr, x, 2048, 256, 1024);
    k_ln_bf<<<2048, 256, 0, stream>>>(x, l2g + i * 256, l2b + i * 256, h);
    k_gemm_bf<128, 128, 1, 0, 1><<<dim3(8, 16), 256, 0, stream>>>(
        h, W1T + (size_t)i * 262144, b1c + (size_t)i * 1024, fbuf, 2048, 1024, 256);
    k_gemm_bf<64, 64, 0, 1, 0><<<dim3(4, 32), 256, 0, stream>>>(
        fbuf, W2T + (size_t)i * 262144, b2c + (size_t)i * 256, x, 2048, 256, 1024);
  }
  k_ln_out<<<2048, 256, 0, stream>>>(x, goc, beo, d_out, flags);
}

// Round 4
// 291.023 us; speedup vs baseline: 10.7547x; 1.3235x over previous
//
#include <hip/hip_runtime.h>
#include <stdint.h>

#define TOKS 2048
#define SEQ 1024

typedef __attribute__((ext_vector_type(8))) short short8;
typedef __attribute__((ext_vector_type(4))) short short4v;
typedef __attribute__((ext_vector_type(4))) float f32x4;

// ---------------- dtype helpers ----------------
__device__ __forceinline__ float loadf(const void* p, size_t i, int isbf16) {
  if (isbf16) {
    unsigned short u = ((const unsigned short*)p)[i];
    return __uint_as_float(((unsigned)u) << 16);
  }
  return ((const float*)p)[i];
}
__device__ __forceinline__ unsigned short f32_to_bf16(float f) {
  unsigned u = __float_as_uint(f);
  unsigned r = u + 0x7FFFu + ((u >> 16) & 1u);
  return (unsigned short)(r >> 16);
}
__device__ __forceinline__ float bf2f(unsigned short u) {
  return __uint_as_float(((unsigned)u) << 16);
}

// ---------------- detection ----------------
__global__ void k_detect(const void* fs, const void* bs, int* flags) {
  int lane = threadIdx.x;
  int bad = 0;
  for (int i = lane; i < 256; i += 64) {
    unsigned short u = ((const unsigned short*)fs)[i];
    float v = __uint_as_float(((unsigned)u) << 16);
    if (!(fabsf(v) <= 100.f)) bad = 1;
  }
  int big = 0;
  for (int i = lane; i < 512; i += 64) {
    if (((const unsigned*)bs)[i] > 1u) big = 1;
  }
#pragma unroll
  for (int off = 32; off; off >>= 1) {
    bad |= __shfl_xor(bad, off);
    big |= __shfl_xor(big, off);
  }
  if (lane == 0) { flags[0] = bad ? 0 : 1; flags[1] = big ? 1 : 0; }
}

// ---------------- plain f32 canonicalization ----------------
struct ConvEntry { const void* src; float* dst; int n; };
struct ConvArgs { ConvEntry e[25]; };

__global__ void k_convert_many(ConvArgs ca, const int* __restrict__ flags) {
  int isbf = flags[0];
  ConvEntry E = ca.e[blockIdx.y];
  for (int i = blockIdx.x * 256 + threadIdx.x; i < E.n; i += gridDim.x * 256)
    E.dst[i] = loadf(E.src, (size_t)i, isbf);
}

__global__ void k_convert_bools(const void* pad, const void* msk,
                                unsigned char* pb, unsigned char* mb,
                                const int* __restrict__ flags) {
  int isb = flags[1];
  int i = blockIdx.x * 256 + threadIdx.x;
  if (i < TOKS) {
    if (isb) {
      pb[i] = ((const unsigned char*)pad)[i] ? 1 : 0;
      mb[i] = ((const unsigned char*)msk)[i] ? 1 : 0;
    } else {
      pb[i] = (((const int*)pad)[i] != 0) ? 1 : 0;
      mb[i] = (((const int*)msk)[i] != 0) ? 1 : 0;
    }
  }
}

// ---------------- transposed bf16 weight conversion ----------------
struct TEntry { const void* src; unsigned short* dst; int soff, K, N, pitch; };
struct TArgs { TEntry e[36]; };

__global__ __launch_bounds__(256) void k_conv_T(TArgs ta, const int* __restrict__ flags) {
  int isbf = flags[0];
  TEntry E = ta.e[blockIdx.y];
  int ktiles = E.K >> 5, ntiles = E.N >> 5;
  if ((int)blockIdx.x >= ktiles * ntiles) return;
  int tk = blockIdx.x % ktiles, tn = blockIdx.x / ktiles;
  __shared__ float t[32][33];
  int tx = threadIdx.x & 31, ty = threadIdx.x >> 5;
#pragma unroll
  for (int s = 0; s < 4; s++) {
    int k = tk * 32 + ty + s * 8, n = tn * 32 + tx;
    t[ty + s * 8][tx] = loadf(E.src, (size_t)E.soff + (size_t)k * E.N + n, isbf);
  }
  __syncthreads();
#pragma unroll
  for (int s = 0; s < 4; s++) {
    int n = tn * 32 + ty + s * 8, k = tk * 32 + tx;
    E.dst[(size_t)n * E.pitch + k] = f32_to_bf16(t[tx][ty + s * 8]);
  }
}

// ---------------- mask words: W2m[z][qg][kc][c] u16, bit (4t+r) ----------------
// z=(b,l); q = qg*4+r; k = kc*64 + t*16 + c
__global__ __launch_bounds__(256) void k_masks2(
    const int* __restrict__ node, const int* __restrict__ f2p,
    const int* __restrict__ colid, const int* __restrict__ tabid,
    const unsigned char* __restrict__ pad_b, unsigned short* __restrict__ W2m) {
  int z = blockIdx.y, qg = blockIdx.x;
  int b = z >> 2, l = z & 3;
  int base = b * SEQ;
  __shared__ int nq[4], cq[4], tq[4], pq[4], fq[4][8];
  int tid = threadIdx.x;
  if (tid < 4) {
    int q = base + qg * 4 + tid;
    nq[tid] = node[q]; cq[tid] = colid[q]; tq[tid] = tabid[q];
    pq[tid] = pad_b[q] ? 0 : 1;
  }
  if (tid < 32) fq[tid >> 3][tid & 7] = f2p[(size_t)(base + qg * 4 + (tid >> 3)) * 8 + (tid & 7)];
  __syncthreads();
  int kc = tid >> 4, c = tid & 15;
  unsigned w = 0;
#pragma unroll
  for (int t = 0; t < 4; t++) {
    int k = base + kc * 64 + t * 16 + c;
    int nk = node[k];
    int pk = pad_b[k] ? 0 : 1;
    int selr[4];
    if (l == 0) {
#pragma unroll
      for (int r = 0; r < 4; r++) {
        int v = (nq[r] == nk);
#pragma unroll
        for (int j2 = 0; j2 < 8; j2++) v |= (fq[r][j2] == nk);
        selr[r] = v;
      }
    } else if (l == 1) {
      const int* fk = &f2p[(size_t)k * 8];
      int f0 = fk[0], f1 = fk[1], f2 = fk[2], f3 = fk[3];
      int f4 = fk[4], f5 = fk[5], f6 = fk[6], f7 = fk[7];
#pragma unroll
      for (int r = 0; r < 4; r++) {
        int n = nq[r];
        selr[r] = (n == f0) | (n == f1) | (n == f2) | (n == f3) |
                  (n == f4) | (n == f5) | (n == f6) | (n == f7);
      }
    } else if (l == 2) {
      int ck = colid[k], tk2 = tabid[k];
#pragma unroll
      for (int r = 0; r < 4; r++) selr[r] = (cq[r] == ck) & (tq[r] == tk2);
    } else {
#pragma unroll
      for (int r = 0; r < 4; r++) selr[r] = 1;
    }
#pragma unroll
    for (int r = 0; r < 4; r++)
      w |= (unsigned)(selr[r] & pk & pq[r]) << (4 * t + r);
  }
  W2m[((size_t)(z * 256 + qg) * 16 + kc) * 16 + c] = (unsigned short)w;
}

// ---------------- block reductions / LN ----------------
__device__ __forceinline__ float block_sum256(float v, float* red) {
#pragma unroll
  for (int off = 32; off; off >>= 1) v += __shfl_xor(v, off);
  int w = threadIdx.x >> 6;
  __syncthreads();
  if ((threadIdx.x & 63) == 0) red[w] = v;
  __syncthreads();
  return red[0] + red[1] + red[2] + red[3];
}
__device__ __forceinline__ float ln256(float y, float* red) {
  float mean = block_sum256(y, red) * (1.0f / 256.0f);
  float dv = y - mean;
  float var = block_sum256(dv * dv, red) * (1.0f / 256.0f);
  return dv * rsqrtf(var + 1e-5f);
}

// ---------------- cell value encoder ----------------
__global__ __launch_bounds__(256) void k_encoder(
    const float* __restrict__ colv, const float* __restrict__ numv,
    const float* __restrict__ textv,
    const float* __restrict__ Wc, const float* __restrict__ bc,
    const float* __restrict__ Wn, const float* __restrict__ bn,
    const float* __restrict__ Wt, const float* __restrict__ bt,
    const float* __restrict__ gc, const float* __restrict__ bec,
    const float* __restrict__ gn, const float* __restrict__ ben,
    const float* __restrict__ gt, const float* __restrict__ bet,
    const float* __restrict__ men, const float* __restrict__ met,
    const unsigned char* __restrict__ pad_b, const unsigned char* __restrict__ msk_b,
    const int* __restrict__ sem, float* __restrict__ x) {
  __shared__ float row[384];
  __shared__ float red[4];
  int token = blockIdx.x, d = threadIdx.x;
  int ispad = pad_b[token];
  float notpad = ispad ? 0.f : 1.f;
  int st = sem[token];
  int mk = msk_b[token];

  for (int i = d; i < 384; i += 256) row[i] = colv[(size_t)token * 384 + i];
  __syncthreads();
  float y = bc[d];
  for (int j = 0; j < 384; j++) y += row[j] * Wc[j * 256 + d];
  float xv = (ln256(y, red) * gc[d] + bec[d]) * notpad;

  {
    float yn = numv[token] * Wn[d] + bn[d];
    float lnv = ln256(yn, red) * gn[d] + ben[d];
    if (st == 0 && !ispad && !mk) xv += lnv;
    if (st == 0 && !ispad && mk)  xv += men[d];
  }
  if (st == 1 && !ispad && !mk) {
    __syncthreads();
    for (int i = d; i < 384; i += 256) row[i] = textv[(size_t)token * 384 + i];
    __syncthreads();
    float yt = bt[d];
    for (int j = 0; j < 384; j++) yt += row[j] * Wt[j * 256 + d];
    xv += ln256(yt, red) * gt[d] + bet[d];
  }
  if (st == 1 && !ispad && mk) xv += met[d];
  x[(size_t)token * 256 + d] = xv;
}

// ---------------- LN kernels ----------------
__global__ __launch_bounds__(256) void k_ln_bf(const float* __restrict__ xin,
                                               const float* __restrict__ g,
                                               const float* __restrict__ b,
                                               unsigned short* __restrict__ out) {
  __shared__ float red[4];
  int token = blockIdx.x, d = threadIdx.x;
  float v = xin[(size_t)token * 256 + d];
  out[(size_t)token * 256 + d] = f32_to_bf16(ln256(v, red) * g[d] + b[d]);
}

__global__ __launch_bounds__(256) void k_ln_out(const float* __restrict__ xin,
                                                const float* __restrict__ g,
                                                const float* __restrict__ b,
                                                void* __restrict__ out,
                                                const int* __restrict__ flags) {
  __shared__ float red[4];
  int token = blockIdx.x, d = threadIdx.x;
  float v = xin[(size_t)token * 256 + d];
  float o = ln256(v, red) * g[d] + b[d];
  size_t idx = (size_t)token * 256 + d;
  if (flags[0]) ((unsigned short*)out)[idx] = f32_to_bf16(o);
  else ((float*)out)[idx] = o;
}

// ---------------- x += p0 + p1 ----------------
__global__ __launch_bounds__(256) void k_add2(float* __restrict__ x,
                                              const float* __restrict__ p0,
                                              const float* __restrict__ p1) {
  int i = blockIdx.x * 256 + threadIdx.x;
  float4 a = ((const float4*)p0)[i];
  float4 b = ((const float4*)p1)[i];
  float4 v = ((float4*)x)[i];
  v.x += a.x + b.x; v.y += a.y + b.y; v.z += a.z + b.z; v.w += a.w + b.w;
  ((float4*)x)[i] = v;
}

// ---------------- bf16 MFMA GEMM ----------------
// OUT: 0 = f32 (partial if KS>1), 1 = bf16, 2 = bf16 + VT-transposed V columns
__device__ __forceinline__ float gelu_tanh(float v) {
  const float c = 0.7978845608028654f;
  float t = tanhf(c * (v + 0.044715f * v * v * v));
  return 0.5f * v * (1.f + t);
}

template <int BM, int BN, int ACT, int OUT, int KS>
__global__ __launch_bounds__(256) void k_gemm_bf(
    const unsigned short* __restrict__ A, const unsigned short* __restrict__ Bt,
    const float* __restrict__ bias, void* __restrict__ Cv,
    unsigned short* __restrict__ VTp,
    int M, int N, int K) {
  __shared__ __align__(16) unsigned short As[BM][40];
  __shared__ __align__(16) unsigned short Bs[BN][40];
  constexpr int FI = BM / 32, FJ = BN / 32;
  int tid = threadIdx.x, wave = tid >> 6, lane = tid & 63;
  int g = lane >> 4, c = lane & 15;
  int wr = wave >> 1, wc = wave & 1;
  int bm = blockIdx.y * BM, bn = blockIdx.x * BN;
  int kz = (KS > 1) ? blockIdx.z : 0;
  f32x4 acc[FI][FJ] = {};
  int sr = tid >> 2, ss = (tid & 3) * 8;
  int kbeg = kz * (K / KS), kend = kbeg + K / KS;

  for (int k0 = kbeg; k0 < kend; k0 += 32) {
    __syncthreads();
#pragma unroll
    for (int rr = 0; rr < BM; rr += 64)
      *(short8*)&As[rr + sr][ss] = *(const short8*)&A[(size_t)(bm + rr + sr) * K + k0 + ss];
#pragma unroll
    for (int rr = 0; rr < BN; rr += 64)
      *(short8*)&Bs[rr + sr][ss] = *(const short8*)&Bt[(size_t)(bn + rr + sr) * K + k0 + ss];
    __syncthreads();
    short8 af[FI], bf[FJ];
#pragma unroll
    for (int i = 0; i < FI; i++) af[i] = *(short8*)&As[wr * (BM / 2) + i * 16 + c][g * 8];
#pragma unroll
    for (int j = 0; j < FJ; j++) bf[j] = *(short8*)&Bs[wc * (BN / 2) + j * 16 + c][g * 8];
#pragma unroll
    for (int i = 0; i < FI; i++)
#pragma unroll
      for (int j = 0; j < FJ; j++)
        acc[i][j] = __builtin_amdgcn_mfma_f32_16x16x32_bf16(af[i], bf[j], acc[i][j], 0, 0, 0);
  }

#pragma unroll
  for (int i = 0; i < FI; i++)
#pragma unroll
    for (int j = 0; j < FJ; j++) {
      int col = bn + wc * (BN / 2) + j * 16 + c;
      int row0 = bm + wr * (BM / 2) + i * 16 + g * 4;
      bool dovt = false;
      if (OUT == 2) {
        int ll = col / 768, cm = col - ll * 768;
        if (cm >= 512) {
          dovt = true;
          short4v pk;
#pragma unroll
          for (int r = 0; r < 4; r++) pk[r] = (short)f32_to_bf16(acc[i][j][r]);
          int bb = row0 >> 10, hh = (cm - 512) >> 5, dd = cm & 31;
          *(short4v*)&VTp[(size_t)(((bb * 4 + ll) * 8 + hh) * 32 + dd) * 1024 + (row0 & 1023)] = pk;
        }
      }
      if (!dovt) {
#pragma unroll
        for (int r = 0; r < 4; r++) {
          float v = acc[i][j][r];
          if (bias && kz == 0) v += bias[col];
          if (ACT) v = gelu_tanh(v);
          size_t idx = (size_t)(row0 + r) * N + col;
          if (OUT == 0) ((float*)Cv)[(size_t)kz * M * N + idx] = v;
          else ((unsigned short*)Cv)[idx] = f32_to_bf16(v);
        }
      }
    }
}

// ---------------- barrier-free MFMA masked flash attention ----------------
// One wave per block, 32 q-rows. grid = 2048: bid = qi*64 + h*8 + z, z=(b,l).
// K read from QKVb (row-major), V from VT (transposed), masks from W2m words.
// No-max softmax: p = ok ? exp(s) : 0 (scores bounded; exact same math).
__global__ __launch_bounds__(64, 4) void k_attn2(
    const unsigned short* __restrict__ QKVb, const unsigned short* __restrict__ W2m,
    const unsigned short* __restrict__ VT, unsigned short* __restrict__ Ocat) {
  __shared__ __align__(16) unsigned short Pl[32][72];
  int bid = blockIdx.x;
  int z = bid & 7, h = (bid >> 3) & 7, qi = bid >> 6;
  int b = z >> 2, l = z & 3;
  int lane = threadIdx.x;
  int g = lane >> 4, c = lane & 15;
  int q0 = qi * 32;
  size_t tokbase = (size_t)b * SEQ;
  int qcol = l * 768 + h * 32;
  int kcol = qcol + 256;
  const unsigned short* vbase = VT + (size_t)(z * 8 + h) * 32 * 1024;
  const unsigned short* mbase = W2m + ((size_t)(z * 256 + (q0 >> 2)) * 16) * 16;

  // Q fragments (scaled)
  short8 qf[2];
#pragma unroll
  for (int s = 0; s < 2; s++) {
    short8 qraw = *(const short8*)&QKVb[(tokbase + q0 + s * 16 + c) * 3072 + qcol + g * 8];
    const float sc = 0.17677669529663687f;
#pragma unroll
    for (int j = 0; j < 8; j++)
      qf[s][j] = (short)f32_to_bf16(bf2f((unsigned short)qraw[j]) * sc);
  }

  f32x4 zero = {0.f, 0.f, 0.f, 0.f};
  f32x4 oacc[2][2];
  oacc[0][0] = zero; oacc[0][1] = zero; oacc[1][0] = zero; oacc[1][1] = zero;
  float ls[2][4] = {};

  for (int kc = 0; kc < 16; kc++) {
    int kb0 = kc * 64;
    // K fragments from global (L2-resident, XCD-local)
    short8 kf[4];
#pragma unroll
    for (int t = 0; t < 4; t++)
      kf[t] = *(const short8*)&QKVb[(tokbase + kb0 + t * 16 + c) * 3072 + kcol + g * 8];
    unsigned mw[2];
#pragma unroll
    for (int s = 0; s < 2; s++)
      mw[s] = mbase[((s * 4 + g) * 16 + kc) * 16 + c];

#pragma unroll
    for (int s = 0; s < 2; s++) {
      f32x4 sa[4];
#pragma unroll
      for (int t = 0; t < 4; t++)
        sa[t] = __builtin_amdgcn_mfma_f32_16x16x32_bf16(qf[s], kf[t], zero, 0, 0, 0);
#pragma unroll
      for (int r = 0; r < 4; r++) {
#pragma unroll
        for (int t = 0; t < 4; t++) {
          int ok = (mw[s] >> (4 * t + r)) & 1;
          float p = ok ? __expf(sa[t][r]) : 0.f;
          ls[s][r] += p;
          Pl[s * 16 + g * 4 + r][t * 16 + c] = f32_to_bf16(p);
        }
      }
    }
    // PV: O[s][16q][32d] += P[s] @ V   (VT rows = dims, shared across subs)
#pragma unroll
    for (int k2 = 0; k2 < 2; k2++) {
      short8 v0 = *(const short8*)&vbase[(size_t)c * 1024 + kb0 + k2 * 32 + g * 8];
      short8 v1 = *(const short8*)&vbase[(size_t)(c + 16) * 1024 + kb0 + k2 * 32 + g * 8];
#pragma unroll
      for (int s = 0; s < 2; s++) {
        short8 pa = *(short8*)&Pl[s * 16 + c][k2 * 32 + g * 8];
        oacc[s][0] = __builtin_amdgcn_mfma_f32_16x16x32_bf16(pa, v0, oacc[s][0], 0, 0, 0);
        oacc[s][1] = __builtin_amdgcn_mfma_f32_16x16x32_bf16(pa, v1, oacc[s][1], 0, 0, 0);
      }
    }
  }

#pragma unroll
  for (int s = 0; s < 2; s++)
#pragma unroll
    for (int r = 0; r < 4; r++) {
      float v = ls[s][r];
      v += __shfl_xor(v, 1); v += __shfl_xor(v, 2);
      v += __shfl_xor(v, 4); v += __shfl_xor(v, 8);
      float inv = (v > 0.f) ? (1.f / v) : 0.f;
      size_t row = tokbase + q0 + s * 16 + g * 4 + r;
      unsigned short* op = &Ocat[row * 1024 + l * 256 + h * 32];
      op[c] = f32_to_bf16(oacc[s][0][r] * inv);
      op[c + 16] = f32_to_bf16(oacc[s][1][r] * inv);
    }
}

// ---------------- host ----------------
extern "C" void kernel_launch(void* const* d_in, const int* in_sizes, int n_in,
                              void* d_out, int out_size, void* d_ws, size_t ws_size,
                              hipStream_t stream) {
  (void)n_in; (void)out_size; (void)ws_size;
  char* wsb = (char*)d_ws;
  int* flags = (int*)wsb;
  unsigned char* pad_b = (unsigned char*)(wsb + 256);
  unsigned char* msk_b = (unsigned char*)(wsb + 256 + 2048);
  float* fbase = (float*)(wsb + 8192);
  size_t fo = 0;
  auto alloc = [&](size_t n) { float* p = fbase + fo; fo += (n + 63) & ~(size_t)63; return p; };

  // f32 params
  float* Wc = alloc(98304);  float* bc = alloc(256);
  float* Wn = alloc(256);    float* bn = alloc(256);
  float* Wt = alloc(98304);  float* bt = alloc(256);
  float* gc = alloc(256);    float* bec = alloc(256);
  float* gn = alloc(256);    float* ben = alloc(256);
  float* gt = alloc(256);    float* bet = alloc(256);
  float* men = alloc(256);   float* met = alloc(256);
  float* l1g = alloc(512);   float* l1b = alloc(512);
  float* l2g = alloc(512);   float* l2b = alloc(512);
  float* b1c = alloc(2048);  float* b2c = alloc(512);
  float* goc = alloc(256);   float* beo = alloc(256);
  float* colv = alloc(786432); float* numv = alloc(2048); float* textv = alloc(786432);
  float* x = alloc(524288);
  // bf16 / u16 buffers (allocated in f32 units)
  unsigned short* W2m   = (unsigned short*)alloc(262144);   // 1 MB mask words
  unsigned short* h     = (unsigned short*)alloc(262144);
  unsigned short* WqkvT = (unsigned short*)alloc(786432);
  unsigned short* WoT   = (unsigned short*)alloc(262144);
  unsigned short* W1T   = (unsigned short*)alloc(262144);
  unsigned short* W2T   = (unsigned short*)alloc(262144);
  unsigned short* QKVb  = (unsigned short*)alloc(3145728);  // 12 MB
  unsigned short* Ocat  = (unsigned short*)alloc(1048576);  // 4 MB
  float* VTf            = alloc(1048576);                   // 4 MB: VT during attn
  unsigned short* VT    = (unsigned short*)VTf;
  float* p0 = VTf;                // split-K partials alias VT (disjoint lifetime)
  float* p1 = VTf + 524288;
  unsigned short* fbuf = QKVb;    // FFN hidden aliases QKVb

  k_detect<<<1, 64, 0, stream>>>(d_in[7], d_in[6], flags);
  k_convert_bools<<<8, 256, 0, stream>>>(d_in[4], d_in[6], pad_b, msk_b, flags);

  ConvArgs ca;
  const int idxs[25] = {10, 11, 12, 13, 14, 15, 16, 17, 18, 19, 20, 21, 22, 23,
                        28, 29, 30, 31, 33, 35, 36, 37, 7, 8, 9};
  float* dsts[25] = {Wc, bc, Wn, bn, Wt, bt, gc, bec, gn, ben, gt, bet, men, met,
                     l1g, l1b, l2g, l2b, b1c, b2c, goc, beo, colv, numv, textv};
  for (int t = 0; t < 25; t++) {
    ca.e[t].src = d_in[idxs[t]];
    ca.e[t].dst = dsts[t];
    ca.e[t].n = in_sizes[idxs[t]];
  }
  k_convert_many<<<dim3(64, 25), 256, 0, stream>>>(ca, flags);

  TArgs ta;
  int ne = 0;
  for (int i = 0; i < 2; i++)
    for (int l = 0; l < 4; l++)
      for (int w = 0; w < 3; w++) {
        ta.e[ne].src = d_in[24 + w];
        ta.e[ne].soff = (i * 4 + l) * 65536;
        ta.e[ne].dst = WqkvT + (size_t)i * 786432 + (size_t)(l * 768 + w * 256) * 256;
        ta.e[ne].K = 256; ta.e[ne].N = 256; ta.e[ne].pitch = 256;
        ne++;
      }
  for (int i = 0; i < 2; i++)
    for (int l = 0; l < 4; l++) {
      ta.e[ne].src = d_in[27];
      ta.e[ne].soff = (i * 4 + l) * 65536;
      ta.e[ne].dst = WoT + (size_t)i * 262144 + l * 256;
      ta.e[ne].K = 256; ta.e[ne].N = 256; ta.e[ne].pitch = 1024;
      ne++;
    }
  for (int i = 0; i < 2; i++) {
    ta.e[ne].src = d_in[32];
    ta.e[ne].soff = i * 262144;
    ta.e[ne].dst = W1T + (size_t)i * 262144;
    ta.e[ne].K = 256; ta.e[ne].N = 1024; ta.e[ne].pitch = 256;
    ne++;
  }
  for (int i = 0; i < 2; i++) {
    ta.e[ne].src = d_in[34];
    ta.e[ne].soff = i * 262144;
    ta.e[ne].dst = W2T + (size_t)i * 262144;
    ta.e[ne].K = 1024; ta.e[ne].N = 256; ta.e[ne].pitch = 1024;
    ne++;
  }
  k_conv_T<<<dim3(256, 36), 256, 0, stream>>>(ta, flags);

  k_masks2<<<dim3(256, 8), 256, 0, stream>>>(
      (const int*)d_in[0], (const int*)d_in[1], (const int*)d_in[2],
      (const int*)d_in[3], pad_b, W2m);
  k_encoder<<<2048, 256, 0, stream>>>(colv, numv, textv, Wc, bc, Wn, bn, Wt, bt,
                                      gc, bec, gn, ben, gt, bet, men, met,
                                      pad_b, msk_b, (const int*)d_in[5], x);
  for (int i = 0; i < 2; i++) {
    k_ln_bf<<<2048, 256, 0, stream>>>(x, l1g + i * 256, l1b + i * 256, h);
    k_gemm_bf<128, 128, 0, 2, 1><<<dim3(24, 16), 256, 0, stream>>>(
        h, WqkvT + (size_t)i * 786432, nullptr, QKVb, VT, 2048, 3072, 256);
    k_attn2<<<2048, 64, 0, stream>>>(QKVb, W2m, VT, Ocat);
    k_gemm_bf<64, 64, 0, 0, 2><<<dim3(4, 32, 2), 256, 0, stream>>>(
        Ocat, WoT + (size_t)i * 262144, nullptr, p0, nullptr, 2048, 256, 1024);
    k_add2<<<512, 256, 0, stream>>>(x, p0, p1);
    k_ln_bf<<<2048, 256, 0, stream>>>(x, l2g + i * 256, l2b + i * 256, h);
    k_gemm_bf<128, 64, 1, 1, 1><<<dim3(16, 16), 256, 0, stream>>>(
        h, W1T + (size_t)i * 262144, b1c + (size_t)i * 1024, fbuf, nullptr, 2048, 1024, 256);
    k_gemm_bf<64, 64, 0, 0, 2><<<dim3(4, 32, 2), 256, 0, stream>>>(
        fbuf, W2T + (size_t)i * 262144, b2c + (size_t)i * 256, p0, nullptr, 2048, 256, 1024);
    k_add2<<<512, 256, 0, stream>>>(x, p0, p1);
  }
  k_ln_out<<<2048, 256, 0, stream>>>(x, goc, beo, d_out, flags);
}

// Round 5
// 272.302 us; speedup vs baseline: 11.4941x; 1.0687x over previous
//
#include <hip/hip_runtime.h>
#include <stdint.h>

#define TOKS 2048
#define SEQ 1024

typedef __attribute__((ext_vector_type(8))) short short8;
typedef __attribute__((ext_vector_type(4))) short short4v;
typedef __attribute__((ext_vector_type(4))) float f32x4;

// ---------------- dtype helpers ----------------
__device__ __forceinline__ float loadf(const void* p, size_t i, int isbf16) {
  if (isbf16) {
    unsigned short u = ((const unsigned short*)p)[i];
    return __uint_as_float(((unsigned)u) << 16);
  }
  return ((const float*)p)[i];
}
__device__ __forceinline__ unsigned short f32_to_bf16(float f) {
  unsigned u = __float_as_uint(f);
  unsigned r = u + 0x7FFFu + ((u >> 16) & 1u);
  return (unsigned short)(r >> 16);
}
__device__ __forceinline__ float bf2f(unsigned short u) {
  return __uint_as_float(((unsigned)u) << 16);
}

// ---------------- detection ----------------
__global__ void k_detect(const void* fs, const void* bs, int* flags) {
  int lane = threadIdx.x;
  int bad = 0;
  for (int i = lane; i < 256; i += 64) {
    unsigned short u = ((const unsigned short*)fs)[i];
    float v = __uint_as_float(((unsigned)u) << 16);
    if (!(fabsf(v) <= 100.f)) bad = 1;
  }
  int big = 0;
  for (int i = lane; i < 512; i += 64) {
    if (((const unsigned*)bs)[i] > 1u) big = 1;
  }
#pragma unroll
  for (int off = 32; off; off >>= 1) {
    bad |= __shfl_xor(bad, off);
    big |= __shfl_xor(big, off);
  }
  if (lane == 0) { flags[0] = bad ? 0 : 1; flags[1] = big ? 1 : 0; }
}

// ---------------- canonicalization ----------------
struct ConvEntry { const void* src; float* dst; int n; };
struct ConvArgs { ConvEntry e[21]; };

__global__ void k_convert_many(ConvArgs ca, const int* __restrict__ flags) {
  int isbf = flags[0];
  ConvEntry E = ca.e[blockIdx.y];
  for (int i = blockIdx.x * 256 + threadIdx.x; i < E.n; i += gridDim.x * 256)
    E.dst[i] = loadf(E.src, (size_t)i, isbf);
}

// f32/bf16 -> bf16 row-major copy (n multiple of 4)
__global__ void k_conv_bf(const void* src, unsigned short* __restrict__ dst,
                          int n, const int* __restrict__ flags) {
  int isbf = flags[0];
  int i = (blockIdx.x * 256 + threadIdx.x) * 4;
  if (i < n) {
#pragma unroll
    for (int j = 0; j < 4; j++) dst[i + j] = f32_to_bf16(loadf(src, i + j, isbf));
  }
}

__global__ void k_convert_bools(const void* pad, const void* msk,
                                unsigned char* pb, unsigned char* mb,
                                const int* __restrict__ flags) {
  int isb = flags[1];
  int i = blockIdx.x * 256 + threadIdx.x;
  if (i < TOKS) {
    if (isb) {
      pb[i] = ((const unsigned char*)pad)[i] ? 1 : 0;
      mb[i] = ((const unsigned char*)msk)[i] ? 1 : 0;
    } else {
      pb[i] = (((const int*)pad)[i] != 0) ? 1 : 0;
      mb[i] = (((const int*)msk)[i] != 0) ? 1 : 0;
    }
  }
}

// ---------------- transposed bf16 weight conversion ----------------
struct TEntry { const void* src; unsigned short* dst; int soff, K, N, pitch; };
struct TArgs { TEntry e[38]; };

__global__ __launch_bounds__(256) void k_conv_T(TArgs ta, const int* __restrict__ flags) {
  int isbf = flags[0];
  TEntry E = ta.e[blockIdx.y];
  int ktiles = E.K >> 5, ntiles = E.N >> 5;
  if ((int)blockIdx.x >= ktiles * ntiles) return;
  int tk = blockIdx.x % ktiles, tn = blockIdx.x / ktiles;
  __shared__ float t[32][33];
  int tx = threadIdx.x & 31, ty = threadIdx.x >> 5;
#pragma unroll
  for (int s = 0; s < 4; s++) {
    int k = tk * 32 + ty + s * 8, n = tn * 32 + tx;
    t[ty + s * 8][tx] = loadf(E.src, (size_t)E.soff + (size_t)k * E.N + n, isbf);
  }
  __syncthreads();
#pragma unroll
  for (int s = 0; s < 4; s++) {
    int n = tn * 32 + ty + s * 8, k = tk * 32 + tx;
    E.dst[(size_t)n * E.pitch + k] = f32_to_bf16(t[tx][ty + s * 8]);
  }
}

// ---------------- mask words ----------------
__global__ __launch_bounds__(256) void k_masks2(
    const int* __restrict__ node, const int* __restrict__ f2p,
    const int* __restrict__ colid, const int* __restrict__ tabid,
    const unsigned char* __restrict__ pad_b, unsigned short* __restrict__ W2m) {
  int z = blockIdx.y, qg = blockIdx.x;
  int b = z >> 2, l = z & 3;
  int base = b * SEQ;
  __shared__ int nq[4], cq[4], tq[4], pq[4], fq[4][8];
  int tid = threadIdx.x;
  if (tid < 4) {
    int q = base + qg * 4 + tid;
    nq[tid] = node[q]; cq[tid] = colid[q]; tq[tid] = tabid[q];
    pq[tid] = pad_b[q] ? 0 : 1;
  }
  if (tid < 32) fq[tid >> 3][tid & 7] = f2p[(size_t)(base + qg * 4 + (tid >> 3)) * 8 + (tid & 7)];
  __syncthreads();
  int kc = tid >> 4, c = tid & 15;
  unsigned w = 0;
#pragma unroll
  for (int t = 0; t < 4; t++) {
    int k = base + kc * 64 + t * 16 + c;
    int nk = node[k];
    int pk = pad_b[k] ? 0 : 1;
    int selr[4];
    if (l == 0) {
#pragma unroll
      for (int r = 0; r < 4; r++) {
        int v = (nq[r] == nk);
#pragma unroll
        for (int j2 = 0; j2 < 8; j2++) v |= (fq[r][j2] == nk);
        selr[r] = v;
      }
    } else if (l == 1) {
      const int* fk = &f2p[(size_t)k * 8];
      int f0 = fk[0], f1 = fk[1], f2 = fk[2], f3 = fk[3];
      int f4 = fk[4], f5 = fk[5], f6 = fk[6], f7 = fk[7];
#pragma unroll
      for (int r = 0; r < 4; r++) {
        int n = nq[r];
        selr[r] = (n == f0) | (n == f1) | (n == f2) | (n == f3) |
                  (n == f4) | (n == f5) | (n == f6) | (n == f7);
      }
    } else if (l == 2) {
      int ck = colid[k], tk2 = tabid[k];
#pragma unroll
      for (int r = 0; r < 4; r++) selr[r] = (cq[r] == ck) & (tq[r] == tk2);
    } else {
#pragma unroll
      for (int r = 0; r < 4; r++) selr[r] = 1;
    }
#pragma unroll
    for (int r = 0; r < 4; r++)
      w |= (unsigned)(selr[r] & pk & pq[r]) << (4 * t + r);
  }
  W2m[((size_t)(z * 256 + qg) * 16 + kc) * 16 + c] = (unsigned short)w;
}

// ---------------- block reductions / LN ----------------
__device__ __forceinline__ float block_sum256(float v, float* red) {
#pragma unroll
  for (int off = 32; off; off >>= 1) v += __shfl_xor(v, off);
  int w = threadIdx.x >> 6;
  __syncthreads();
  if ((threadIdx.x & 63) == 0) red[w] = v;
  __syncthreads();
  return red[0] + red[1] + red[2] + red[3];
}
__device__ __forceinline__ float ln256(float y, float* red) {
  float mean = block_sum256(y, red) * (1.0f / 256.0f);
  float dv = y - mean;
  float var = block_sum256(dv * dv, red) * (1.0f / 256.0f);
  return dv * rsqrtf(var + 1e-5f);
}

// ---------------- encoder pointwise (after MFMA GEMMs) ----------------
__global__ __launch_bounds__(256) void k_encoder2(
    const float* __restrict__ Yc, const float* __restrict__ Yt,
    const float* __restrict__ numv,
    const float* __restrict__ Wn, const float* __restrict__ bn,
    const float* __restrict__ gc, const float* __restrict__ bec,
    const float* __restrict__ gn, const float* __restrict__ ben,
    const float* __restrict__ gt, const float* __restrict__ bet,
    const float* __restrict__ men, const float* __restrict__ met,
    const unsigned char* __restrict__ pad_b, const unsigned char* __restrict__ msk_b,
    const int* __restrict__ sem, float* __restrict__ x) {
  __shared__ float red[4];
  int token = blockIdx.x, d = threadIdx.x;
  int ispad = pad_b[token];
  float notpad = ispad ? 0.f : 1.f;
  int st = sem[token];
  int mk = msk_b[token];

  float yc = Yc[(size_t)token * 256 + d];
  float xv = (ln256(yc, red) * gc[d] + bec[d]) * notpad;

  {
    float yn = numv[token] * Wn[d] + bn[d];
    float lnv = ln256(yn, red) * gn[d] + ben[d];
    if (st == 0 && !ispad && !mk) xv += lnv;
    if (st == 0 && !ispad && mk)  xv += men[d];
  }
  if (st == 1 && !ispad && !mk) {   // block-uniform branch
    float yt = Yt[(size_t)token * 256 + d];
    xv += ln256(yt, red) * gt[d] + bet[d];
  }
  if (st == 1 && !ispad && mk) xv += met[d];
  x[(size_t)token * 256 + d] = xv;
}

// ---------------- LN kernels ----------------
__global__ __launch_bounds__(256) void k_ln_bf(const float* __restrict__ xin,
                                               const float* __restrict__ g,
                                               const float* __restrict__ b,
                                               unsigned short* __restrict__ out) {
  __shared__ float red[4];
  int token = blockIdx.x, d = threadIdx.x;
  float v = xin[(size_t)token * 256 + d];
  out[(size_t)token * 256 + d] = f32_to_bf16(ln256(v, red) * g[d] + b[d]);
}

// x += p0+p1; out = bf16(LN(x)*g+b)
__global__ __launch_bounds__(256) void k_ln_add_bf(float* __restrict__ x,
                                                   const float* __restrict__ p0,
                                                   const float* __restrict__ p1,
                                                   const float* __restrict__ g,
                                                   const float* __restrict__ b,
                                                   unsigned short* __restrict__ out) {
  __shared__ float red[4];
  int token = blockIdx.x, d = threadIdx.x;
  size_t i = (size_t)token * 256 + d;
  float v = x[i] + p0[i] + p1[i];
  x[i] = v;
  out[i] = f32_to_bf16(ln256(v, red) * g[d] + b[d]);
}

__global__ __launch_bounds__(256) void k_ln_out_add(const float* __restrict__ xin,
                                                    const float* __restrict__ p0,
                                                    const float* __restrict__ p1,
                                                    const float* __restrict__ g,
                                                    const float* __restrict__ b,
                                                    void* __restrict__ out,
                                                    const int* __restrict__ flags) {
  __shared__ float red[4];
  int token = blockIdx.x, d = threadIdx.x;
  size_t idx = (size_t)token * 256 + d;
  float v = xin[idx] + p0[idx] + p1[idx];
  float o = ln256(v, red) * g[d] + b[d];
  if (flags[0]) ((unsigned short*)out)[idx] = f32_to_bf16(o);
  else ((float*)out)[idx] = o;
}

// ---------------- bf16 MFMA GEMM ----------------
__device__ __forceinline__ float gelu_tanh(float v) {
  const float c = 0.7978845608028654f;
  float t = tanhf(c * (v + 0.044715f * v * v * v));
  return 0.5f * v * (1.f + t);
}

template <int BM, int BN, int ACT, int OUT, int KS>
__global__ __launch_bounds__(256) void k_gemm_bf(
    const unsigned short* __restrict__ A, const unsigned short* __restrict__ Bt,
    const float* __restrict__ bias, void* __restrict__ Cv,
    unsigned short* __restrict__ VTp,
    int M, int N, int K) {
  __shared__ __align__(16) unsigned short As[BM][40];
  __shared__ __align__(16) unsigned short Bs[BN][40];
  constexpr int FI = BM / 32, FJ = BN / 32;
  int tid = threadIdx.x, wave = tid >> 6, lane = tid & 63;
  int g = lane >> 4, c = lane & 15;
  int wr = wave >> 1, wc = wave & 1;
  int bm = blockIdx.y * BM, bn = blockIdx.x * BN;
  int kz = (KS > 1) ? blockIdx.z : 0;
  f32x4 acc[FI][FJ] = {};
  int sr = tid >> 2, ss = (tid & 3) * 8;
  int kbeg = kz * (K / KS), kend = kbeg + K / KS;

  for (int k0 = kbeg; k0 < kend; k0 += 32) {
    __syncthreads();
#pragma unroll
    for (int rr = 0; rr < BM; rr += 64)
      *(short8*)&As[rr + sr][ss] = *(const short8*)&A[(size_t)(bm + rr + sr) * K + k0 + ss];
#pragma unroll
    for (int rr = 0; rr < BN; rr += 64)
      *(short8*)&Bs[rr + sr][ss] = *(const short8*)&Bt[(size_t)(bn + rr + sr) * K + k0 + ss];
    __syncthreads();
    short8 af[FI], bf[FJ];
#pragma unroll
    for (int i = 0; i < FI; i++) af[i] = *(short8*)&As[wr * (BM / 2) + i * 16 + c][g * 8];
#pragma unroll
    for (int j = 0; j < FJ; j++) bf[j] = *(short8*)&Bs[wc * (BN / 2) + j * 16 + c][g * 8];
#pragma unroll
    for (int i = 0; i < FI; i++)
#pragma unroll
      for (int j = 0; j < FJ; j++)
        acc[i][j] = __builtin_amdgcn_mfma_f32_16x16x32_bf16(af[i], bf[j], acc[i][j], 0, 0, 0);
  }

#pragma unroll
  for (int i = 0; i < FI; i++)
#pragma unroll
    for (int j = 0; j < FJ; j++) {
      int col = bn + wc * (BN / 2) + j * 16 + c;
      int row0 = bm + wr * (BM / 2) + i * 16 + g * 4;
      bool dovt = false;
      if (OUT == 2) {
        int ll = col / 768, cm = col - ll * 768;
        if (cm >= 512) {
          dovt = true;
          short4v pk;
#pragma unroll
          for (int r = 0; r < 4; r++) pk[r] = (short)f32_to_bf16(acc[i][j][r]);
          int bb = row0 >> 10, hh = (cm - 512) >> 5, dd = cm & 31;
          *(short4v*)&VTp[(size_t)(((bb * 4 + ll) * 8 + hh) * 32 + dd) * 1024 + (row0 & 1023)] = pk;
        }
      }
      if (!dovt) {
#pragma unroll
        for (int r = 0; r < 4; r++) {
          float v = acc[i][j][r];
          if (bias && kz == 0) v += bias[col];
          if (ACT) v = gelu_tanh(v);
          size_t idx = (size_t)(row0 + r) * N + col;
          if (OUT == 0) ((float*)Cv)[(size_t)kz * M * N + idx] = v;
          else ((unsigned short*)Cv)[idx] = f32_to_bf16(v);
        }
      }
    }
}

// ---------------- barrier-free MFMA masked flash attention ----------------
__global__ __launch_bounds__(64, 4) void k_attn2(
    const unsigned short* __restrict__ QKVb, const unsigned short* __restrict__ W2m,
    const unsigned short* __restrict__ VT, unsigned short* __restrict__ Ocat) {
  __shared__ __align__(16) unsigned short Pl[32][72];
  int bid = blockIdx.x;
  int z = bid & 7, h = (bid >> 3) & 7, qi = bid >> 6;
  int b = z >> 2, l = z & 3;
  int lane = threadIdx.x;
  int g = lane >> 4, c = lane & 15;
  int q0 = qi * 32;
  size_t tokbase = (size_t)b * SEQ;
  int qcol = l * 768 + h * 32;
  int kcol = qcol + 256;
  const unsigned short* vbase = VT + (size_t)(z * 8 + h) * 32 * 1024;
  const unsigned short* mbase = W2m + ((size_t)(z * 256 + (q0 >> 2)) * 16) * 16;

  short8 qf[2];
#pragma unroll
  for (int s = 0; s < 2; s++) {
    short8 qraw = *(const short8*)&QKVb[(tokbase + q0 + s * 16 + c) * 3072 + qcol + g * 8];
    const float sc = 0.17677669529663687f;
#pragma unroll
    for (int j = 0; j < 8; j++)
      qf[s][j] = (short)f32_to_bf16(bf2f((unsigned short)qraw[j]) * sc);
  }

  f32x4 zero = {0.f, 0.f, 0.f, 0.f};
  f32x4 oacc[2][2];
  oacc[0][0] = zero; oacc[0][1] = zero; oacc[1][0] = zero; oacc[1][1] = zero;
  float ls[2][4] = {};

  for (int kc = 0; kc < 16; kc++) {
    int kb0 = kc * 64;
    short8 kf[4];
#pragma unroll
    for (int t = 0; t < 4; t++)
      kf[t] = *(const short8*)&QKVb[(tokbase + kb0 + t * 16 + c) * 3072 + kcol + g * 8];
    unsigned mw[2];
#pragma unroll
    for (int s = 0; s < 2; s++)
      mw[s] = mbase[((s * 4 + g) * 16 + kc) * 16 + c];

#pragma unroll
    for (int s = 0; s < 2; s++) {
      f32x4 sa[4];
#pragma unroll
      for (int t = 0; t < 4; t++)
        sa[t] = __builtin_amdgcn_mfma_f32_16x16x32_bf16(qf[s], kf[t], zero, 0, 0, 0);
#pragma unroll
      for (int r = 0; r < 4; r++) {
#pragma unroll
        for (int t = 0; t < 4; t++) {
          int ok = (mw[s] >> (4 * t + r)) & 1;
          float p = ok ? __expf(sa[t][r]) : 0.f;
          ls[s][r] += p;
          Pl[s * 16 + g * 4 + r][t * 16 + c] = f32_to_bf16(p);
        }
      }
    }
#pragma unroll
    for (int k2 = 0; k2 < 2; k2++) {
      short8 v0 = *(const short8*)&vbase[(size_t)c * 1024 + kb0 + k2 * 32 + g * 8];
      short8 v1 = *(const short8*)&vbase[(size_t)(c + 16) * 1024 + kb0 + k2 * 32 + g * 8];
#pragma unroll
      for (int s = 0; s < 2; s++) {
        short8 pa = *(short8*)&Pl[s * 16 + c][k2 * 32 + g * 8];
        oacc[s][0] = __builtin_amdgcn_mfma_f32_16x16x32_bf16(pa, v0, oacc[s][0], 0, 0, 0);
        oacc[s][1] = __builtin_amdgcn_mfma_f32_16x16x32_bf16(pa, v1, oacc[s][1], 0, 0, 0);
      }
    }
  }

#pragma unroll
  for (int s = 0; s < 2; s++)
#pragma unroll
    for (int r = 0; r < 4; r++) {
      float v = ls[s][r];
      v += __shfl_xor(v, 1); v += __shfl_xor(v, 2);
      v += __shfl_xor(v, 4); v += __shfl_xor(v, 8);
      float inv = (v > 0.f) ? (1.f / v) : 0.f;
      size_t row = tokbase + q0 + s * 16 + g * 4 + r;
      unsigned short* op = &Ocat[row * 1024 + l * 256 + h * 32];
      op[c] = f32_to_bf16(oacc[s][0][r] * inv);
      op[c + 16] = f32_to_bf16(oacc[s][1][r] * inv);
    }
}

// ---------------- host ----------------
extern "C" void kernel_launch(void* const* d_in, const int* in_sizes, int n_in,
                              void* d_out, int out_size, void* d_ws, size_t ws_size,
                              hipStream_t stream) {
  (void)n_in; (void)out_size; (void)ws_size;
  char* wsb = (char*)d_ws;
  int* flags = (int*)wsb;
  unsigned char* pad_b = (unsigned char*)(wsb + 256);
  unsigned char* msk_b = (unsigned char*)(wsb + 256 + 2048);
  float* fbase = (float*)(wsb + 8192);
  size_t fo = 0;
  auto alloc = [&](size_t n) { float* p = fbase + fo; fo += (n + 63) & ~(size_t)63; return p; };

  // f32 params
  float* bc = alloc(256);
  float* Wn = alloc(256);    float* bn = alloc(256);
  float* bt = alloc(256);
  float* gc = alloc(256);    float* bec = alloc(256);
  float* gn = alloc(256);    float* ben = alloc(256);
  float* gt = alloc(256);    float* bet = alloc(256);
  float* men = alloc(256);   float* met = alloc(256);
  float* l1g = alloc(512);   float* l1b = alloc(512);
  float* l2g = alloc(512);   float* l2b = alloc(512);
  float* b1c = alloc(2048);  float* b2c = alloc(512);
  float* goc = alloc(256);   float* beo = alloc(256);
  float* numv = alloc(2048);
  float* x = alloc(524288);
  // bf16 / u16 buffers
  unsigned short* W2m   = (unsigned short*)alloc(262144);
  unsigned short* h     = (unsigned short*)alloc(262144);
  unsigned short* WqkvT = (unsigned short*)alloc(786432);
  unsigned short* WoT   = (unsigned short*)alloc(262144);
  unsigned short* W1T   = (unsigned short*)alloc(262144);
  unsigned short* W2T   = (unsigned short*)alloc(262144);
  unsigned short* WcT   = (unsigned short*)alloc(49152);   // 256x384
  unsigned short* WtT   = (unsigned short*)alloc(49152);
  unsigned short* colvb = (unsigned short*)alloc(393216);  // 2048x384 bf16
  unsigned short* textvb= (unsigned short*)alloc(393216);
  unsigned short* QKVb  = (unsigned short*)alloc(3145728);
  unsigned short* Ocat  = (unsigned short*)alloc(1048576);
  float* VTf            = alloc(1048576);
  unsigned short* VT    = (unsigned short*)VTf;
  float* p0 = VTf;                 // aliases: Yc / split-K partial 0
  float* p1 = VTf + 524288;        // aliases: Yt / split-K partial 1
  unsigned short* fbuf = QKVb;

  k_detect<<<1, 64, 0, stream>>>(d_in[7], d_in[6], flags);
  k_convert_bools<<<8, 256, 0, stream>>>(d_in[4], d_in[6], pad_b, msk_b, flags);

  ConvArgs ca;
  const int idxs[21] = {11, 12, 13, 15, 16, 17, 18, 19, 20, 21, 22, 23,
                        28, 29, 30, 31, 33, 35, 36, 37, 8};
  float* dsts[21] = {bc, Wn, bn, bt, gc, bec, gn, ben, gt, bet, men, met,
                     l1g, l1b, l2g, l2b, b1c, b2c, goc, beo, numv};
  for (int t = 0; t < 21; t++) {
    ca.e[t].src = d_in[idxs[t]];
    ca.e[t].dst = dsts[t];
    ca.e[t].n = in_sizes[idxs[t]];
  }
  k_convert_many<<<dim3(8, 21), 256, 0, stream>>>(ca, flags);
  k_conv_bf<<<768, 256, 0, stream>>>(d_in[7], colvb, 786432, flags);
  k_conv_bf<<<768, 256, 0, stream>>>(d_in[9], textvb, 786432, flags);

  TArgs ta;
  int ne = 0;
  for (int i = 0; i < 2; i++)
    for (int l = 0; l < 4; l++)
      for (int w = 0; w < 3; w++) {
        ta.e[ne].src = d_in[24 + w];
        ta.e[ne].soff = (i * 4 + l) * 65536;
        ta.e[ne].dst = WqkvT + (size_t)i * 786432 + (size_t)(l * 768 + w * 256) * 256;
        ta.e[ne].K = 256; ta.e[ne].N = 256; ta.e[ne].pitch = 256;
        ne++;
      }
  for (int i = 0; i < 2; i++)
    for (int l = 0; l < 4; l++) {
      ta.e[ne].src = d_in[27];
      ta.e[ne].soff = (i * 4 + l) * 65536;
      ta.e[ne].dst = WoT + (size_t)i * 262144 + l * 256;
      ta.e[ne].K = 256; ta.e[ne].N = 256; ta.e[ne].pitch = 1024;
      ne++;
    }
  for (int i = 0; i < 2; i++) {
    ta.e[ne].src = d_in[32];
    ta.e[ne].soff = i * 262144;
    ta.e[ne].dst = W1T + (size_t)i * 262144;
    ta.e[ne].K = 256; ta.e[ne].N = 1024; ta.e[ne].pitch = 256;
    ne++;
  }
  for (int i = 0; i < 2; i++) {
    ta.e[ne].src = d_in[34];
    ta.e[ne].soff = i * 262144;
    ta.e[ne].dst = W2T + (size_t)i * 262144;
    ta.e[ne].K = 1024; ta.e[ne].N = 256; ta.e[ne].pitch = 1024;
    ne++;
  }
  ta.e[ne].src = d_in[10]; ta.e[ne].soff = 0; ta.e[ne].dst = WcT;
  ta.e[ne].K = 384; ta.e[ne].N = 256; ta.e[ne].pitch = 384; ne++;
  ta.e[ne].src = d_in[14]; ta.e[ne].soff = 0; ta.e[ne].dst = WtT;
  ta.e[ne].K = 384; ta.e[ne].N = 256; ta.e[ne].pitch = 384; ne++;
  k_conv_T<<<dim3(256, 38), 256, 0, stream>>>(ta, flags);

  k_masks2<<<dim3(256, 8), 256, 0, stream>>>(
      (const int*)d_in[0], (const int*)d_in[1], (const int*)d_in[2],
      (const int*)d_in[3], pad_b, W2m);

  // encoder: Yc = colv@Wc + bc, Yt = textv@Wt + bt (MFMA), then pointwise
  k_gemm_bf<128, 128, 0, 0, 1><<<dim3(2, 16), 256, 0, stream>>>(
      colvb, WcT, bc, p0, nullptr, 2048, 256, 384);
  k_gemm_bf<128, 128, 0, 0, 1><<<dim3(2, 16), 256, 0, stream>>>(
      textvb, WtT, bt, p1, nullptr, 2048, 256, 384);
  k_encoder2<<<2048, 256, 0, stream>>>(p0, p1, numv, Wn, bn, gc, bec, gn, ben,
                                       gt, bet, men, met, pad_b, msk_b,
                                       (const int*)d_in[5], x);

  k_ln_bf<<<2048, 256, 0, stream>>>(x, l1g, l1b, h);
  for (int i = 0; i < 2; i++) {
    k_gemm_bf<128, 128, 0, 2, 1><<<dim3(24, 16), 256, 0, stream>>>(
        h, WqkvT + (size_t)i * 786432, nullptr, QKVb, VT, 2048, 3072, 256);
    k_attn2<<<2048, 64, 0, stream>>>(QKVb, W2m, VT, Ocat);
    k_gemm_bf<64, 64, 0, 0, 2><<<dim3(4, 32, 2), 256, 0, stream>>>(
        Ocat, WoT + (size_t)i * 262144, nullptr, p0, nullptr, 2048, 256, 1024);
    k_ln_add_bf<<<2048, 256, 0, stream>>>(x, p0, p1, l2g + i * 256, l2b + i * 256, h);
    k_gemm_bf<128, 64, 1, 1, 1><<<dim3(16, 16), 256, 0, stream>>>(
        h, W1T + (size_t)i * 262144, b1c + (size_t)i * 1024, fbuf, nullptr, 2048, 1024, 256);
    k_gemm_bf<64, 64, 0, 0, 2><<<dim3(4, 32, 2), 256, 0, stream>>>(
        fbuf, W2T + (size_t)i * 262144, b2c + (size_t)i * 256, p0, nullptr, 2048, 256, 1024);
    if (i == 0)
      k_ln_add_bf<<<2048, 256, 0, stream>>>(x, p0, p1, l1g + 256, l1b + 256, h);
    else
      k_ln_out_add<<<2048, 256, 0, stream>>>(x, p0, p1, goc, beo, d_out, flags);
  }
}